// Round 2
// baseline (6448.308 us; speedup 1.0000x reference)
//
#include <hip/hip_runtime.h>
#include <math.h>

namespace {

constexpr int NB    = 4;
constexpr int L     = 4096;   // SEQ == LDEC
constexpr int PRED  = 2048;
constexpr int LABEL = 2048;
constexpr int NF    = 21;
constexpr int Dm    = 512;
constexpr int NH    = 8;
constexpr int NE    = 64;
constexpr int NM    = 64;
constexpr int DFF   = 2048;
constexpr float TWOPI = 6.283185307179586f;

// ---------------- init: column mean of x_enc over time ----------------
__global__ void k_enc_mean(const float* __restrict__ x, float* __restrict__ mean_bf) {
  int bf = blockIdx.x; int b = bf / NF, f = bf % NF;
  const float* p = x + (size_t)b * L * NF + f;
  float s = 0.f;
  for (int l = threadIdx.x; l < L; l += 256) s += p[(size_t)l * NF];
  __shared__ float red[256];
  red[threadIdx.x] = s; __syncthreads();
  for (int st = 128; st > 0; st >>= 1) {
    if (threadIdx.x < st) red[threadIdx.x] += red[threadIdx.x + st];
    __syncthreads();
  }
  if (threadIdx.x == 0) mean_bf[bf] = red[0] * (1.0f / L);
}

// ---------------- init decomp: seasonal_init / trend_init ----------------
__global__ void k_init_decomp(const float* __restrict__ x, const float* __restrict__ mean_bf,
                              float* __restrict__ sinit, float* __restrict__ tinit) {
  int idx = blockIdx.x * 256 + threadIdx.x;
  if (idx >= NB * L * NF) return;
  int f = idx % NF; int t = (idx / NF) % L; int b = idx / (NF * L);
  float sv, tv;
  if (t < LABEL) {
    int l = LABEL + t;
    float s = 0.f;
    #pragma unroll
    for (int j = -12; j <= 12; ++j) {
      int ll = l + j; ll = ll < 0 ? 0 : (ll > L - 1 ? L - 1 : ll);
      s += x[((size_t)b * L + ll) * NF + f];
    }
    float ma = s * (1.0f / 25.0f);
    sv = x[((size_t)b * L + l) * NF + f] - ma;
    tv = ma;
  } else { sv = 0.f; tv = mean_bf[b * NF + f]; }
  sinit[idx] = sv; tinit[idx] = tv;
}

// ---------------- embedding: circular conv3 (NF->Dm) + positional ----------------
__global__ void k_embed(const float* __restrict__ x, const float* __restrict__ W,
                        float* __restrict__ out) {
  int bl = blockIdx.x;
  int b = bl >> 12, l = bl & (L - 1);
  __shared__ float row[3 * NF];
  int lm = (l - 1) & (L - 1), lp = (l + 1) & (L - 1);
  const float* xb = x + (size_t)b * L * NF;
  int t = threadIdx.x;
  if (t < 3 * NF) {
    int j = t / NF, f = t - j * NF;
    int ll = (j == 0) ? lm : ((j == 1) ? l : lp);
    row[t] = xb[(size_t)ll * NF + f];
  }
  __syncthreads();
  for (int d = t; d < Dm; d += 256) {
    const float* w = W + (size_t)d * NF * 3;
    float acc = 0.f;
    #pragma unroll
    for (int f = 0; f < NF; ++f)
      acc += row[f] * w[f * 3] + row[NF + f] * w[f * 3 + 1] + row[2 * NF + f] * w[f * 3 + 2];
    int i2 = d >> 1;
    float dv = expf((float)(2 * i2) * (-9.210340371976184f / 512.0f));
    float ang = (float)l * dv;
    float pe = (d & 1) ? cosf(ang) : sinf(ang);
    out[((size_t)b * L + l) * Dm + d] = acc + pe;
  }
}

// ---------------- generic fp32 GEMM: C = A @ W^T (+bias)(+gelu)(+res) ----------------
template<bool BIAS, bool RES, bool GELU>
__global__ __launch_bounds__(256) void k_gemm(const float* __restrict__ A, const float* __restrict__ W,
                       const float* __restrict__ bias, const float* __restrict__ R,
                       float* __restrict__ C, int N, int K) {
  __shared__ float As[16][68];
  __shared__ float Ws[16][68];
  int nt = N >> 6;
  int n0 = (blockIdx.x % nt) << 6;
  int m0 = (blockIdx.x / nt) << 6;
  int t = threadIdx.x;
  int tx = t & 15, ty = t >> 4;
  int lr = t >> 2;
  int lc = (t & 3) << 2;
  float acc[4][4] = {};
  for (int k0 = 0; k0 < K; k0 += 16) {
    float4 a4 = *reinterpret_cast<const float4*>(A + (size_t)(m0 + lr) * K + k0 + lc);
    float4 w4 = *reinterpret_cast<const float4*>(W + (size_t)(n0 + lr) * K + k0 + lc);
    As[lc + 0][lr] = a4.x; As[lc + 1][lr] = a4.y; As[lc + 2][lr] = a4.z; As[lc + 3][lr] = a4.w;
    Ws[lc + 0][lr] = w4.x; Ws[lc + 1][lr] = w4.y; Ws[lc + 2][lr] = w4.z; Ws[lc + 3][lr] = w4.w;
    __syncthreads();
    #pragma unroll
    for (int k = 0; k < 16; ++k) {
      float av[4], wv[4];
      #pragma unroll
      for (int i = 0; i < 4; ++i) av[i] = As[k][(ty << 2) + i];
      #pragma unroll
      for (int j = 0; j < 4; ++j) wv[j] = Ws[k][(tx << 2) + j];
      #pragma unroll
      for (int i = 0; i < 4; ++i)
        #pragma unroll
        for (int j = 0; j < 4; ++j) acc[i][j] += av[i] * wv[j];
    }
    __syncthreads();
  }
  #pragma unroll
  for (int i = 0; i < 4; ++i) {
    int m = m0 + (ty << 2) + i;
    #pragma unroll
    for (int j = 0; j < 4; ++j) {
      int n = n0 + (tx << 2) + j;
      float v = acc[i][j];
      if (BIAS) v += bias[n];
      if (GELU) v = 0.5f * v * (1.0f + erff(v * 0.70710678118654752f));
      if (RES)  v += R[(size_t)m * N + n];
      C[(size_t)m * N + n] = v;
    }
  }
}

// ---------------- forward DFT (first 64 bins): S[b,c,0..63]=Re, [64..127]=Im ----------------
__global__ void k_dft(const float* __restrict__ A, float* __restrict__ S) {
  int mt = blockIdx.x & 1, seg = blockIdx.x >> 1;
  int c0 = blockIdx.y << 6;
  int b  = blockIdx.z;
  int m0 = mt << 6;
  __shared__ float As[16][68];
  __shared__ float Fs[16][68];
  int t = threadIdx.x, tx = t & 15, ty = t >> 4;
  int rr = t >> 6, cc = t & 63;
  float acc[4][4] = {};
  const float* Ab = A + (size_t)b * L * Dm;
  int lbeg = seg * (L / 8);
  for (int l0 = lbeg; l0 < lbeg + L / 8; l0 += 16) {
    #pragma unroll
    for (int q = 0; q < 4; ++q) {
      int lr = rr + q * 4;
      As[lr][cc] = Ab[(size_t)(l0 + lr) * Dm + c0 + cc];
      int m2 = m0 + cc;
      int m = m2 & 63;
      int ph = (m * (l0 + lr)) & (L - 1);
      float sv, cv;
      __sincosf((float)ph * (TWOPI / L), &sv, &cv);
      Fs[lr][cc] = (m2 < 64) ? cv : -sv;
    }
    __syncthreads();
    #pragma unroll
    for (int k = 0; k < 16; ++k) {
      float av[4], fv[4];
      #pragma unroll
      for (int i = 0; i < 4; ++i) av[i] = As[k][(ty << 2) + i];
      #pragma unroll
      for (int j = 0; j < 4; ++j) fv[j] = Fs[k][(tx << 2) + j];
      #pragma unroll
      for (int i = 0; i < 4; ++i)
        #pragma unroll
        for (int j = 0; j < 4; ++j) acc[i][j] += av[i] * fv[j];
    }
    __syncthreads();
  }
  #pragma unroll
  for (int i = 0; i < 4; ++i) {
    int c = c0 + (ty << 2) + i;
    #pragma unroll
    for (int j = 0; j < 4; ++j) {
      int m2 = m0 + (tx << 2) + j;
      atomicAdd(&S[((size_t)b * Dm + c) * 128 + m2], acc[i][j]);
    }
  }
}

// ---------------- inverse DFT (64 nonzero bins, numpy C2R: Im(bin0) dropped) ----------------
__global__ void k_irdft(const float* __restrict__ S, float* __restrict__ O, float scale) {
  int l0 = blockIdx.x << 6;
  int c0 = blockIdx.y << 6;
  int b  = blockIdx.z;
  __shared__ float Ss[16][68];
  __shared__ float Gs[16][68];
  int t = threadIdx.x, tx = t & 15, ty = t >> 4;
  int rr = t >> 6, cc = t & 63;
  float acc[4][4] = {};
  for (int m0 = 0; m0 < 128; m0 += 16) {
    #pragma unroll
    for (int q = 0; q < 4; ++q) {
      int kr = rr + q * 4;
      Ss[kr][cc] = S[((size_t)b * Dm + c0 + cc) * 128 + m0 + kr];
      int m2 = m0 + kr;
      int l = l0 + cc;
      float g;
      if (m2 == 0) g = 1.0f;
      else if (m2 == 64) g = 0.0f;
      else {
        int m = m2 & 63;
        int ph = (m * l) & (L - 1);
        float sv, cv;
        __sincosf((float)ph * (TWOPI / L), &sv, &cv);
        g = (m2 < 64) ? 2.0f * cv : -2.0f * sv;
      }
      Gs[kr][cc] = g;
    }
    __syncthreads();
    #pragma unroll
    for (int k = 0; k < 16; ++k) {
      float av[4], gv[4];
      #pragma unroll
      for (int i = 0; i < 4; ++i) av[i] = Ss[k][(ty << 2) + i];
      #pragma unroll
      for (int j = 0; j < 4; ++j) gv[j] = Gs[k][(tx << 2) + j];
      #pragma unroll
      for (int i = 0; i < 4; ++i)
        #pragma unroll
        for (int j = 0; j < 4; ++j) acc[i][j] += av[i] * gv[j];
    }
    __syncthreads();
  }
  #pragma unroll
  for (int i = 0; i < 4; ++i) {
    int c = c0 + (ty << 2) + i;
    #pragma unroll
    for (int j = 0; j < 4; ++j) {
      int l = l0 + (tx << 2) + j;
      O[((size_t)b * Dm + c) * L + l] = acc[i][j] * scale;
    }
  }
}

// ---------------- per-mode complex channel mix: of[b,(h,o),m] = sum_i qf[b,(h,i),m]*W[h,i,o,m] ----------------
__global__ void k_cmul(const float* __restrict__ S, const float* __restrict__ Wf,
                       float* __restrict__ O) {
  int blk = blockIdx.x;
  int m = blk & 63;
  int h = (blk >> 6) & 7;
  int b = blk >> 9;
  int o = threadIdx.x;
  const float* Sb = S + ((size_t)b * Dm + h * NE) * 128;
  const float* Wb = Wf + (size_t)h * NE * NE * NM * 2;
  float ar = 0.f, ai = 0.f;
  for (int i = 0; i < NE; ++i) {
    float qr = Sb[i * 128 + m], qi = Sb[i * 128 + 64 + m];
    const float* w = Wb + (((size_t)i * NE + o) * NM + m) * 2;
    float wr = w[0], wi = w[1];
    ar += qr * wr - qi * wi;
    ai += qr * wi + qi * wr;
  }
  float* Ob = O + ((size_t)b * Dm + h * NE) * 128;
  Ob[o * 128 + m] = ar;
  Ob[o * 128 + 64 + m] = ai;
}

// ---------------- cross: s[x,y] = ctanh(sum_e qf[e,x]*kf[e,y]) ----------------
__global__ void k_cross_s(const float* __restrict__ Sq, const float* __restrict__ Sk,
                          float* __restrict__ Sout) {
  int bh = blockIdx.x;
  int b = bh >> 3, h = bh & 7;
  __shared__ float Qr[64][64], Qi[64][64], Kr[64][64], Ki[64][64];
  int t = threadIdx.x;
  const float* qb = Sq + ((size_t)b * Dm + h * NE) * 128;
  const float* kb = Sk + ((size_t)b * Dm + h * NE) * 128;
  for (int idx = t; idx < 4096; idx += 256) {
    int e = idx >> 6, x = idx & 63;
    Qr[e][x] = qb[e * 128 + x];
    Qi[e][x] = qb[e * 128 + 64 + x];
    Kr[e][x] = kb[e * 128 + x];
    Ki[e][x] = kb[e * 128 + 64 + x];
  }
  __syncthreads();
  int tx = t & 15, ty = t >> 4;
  float ar[4][4] = {}, ai[4][4] = {};
  for (int e = 0; e < 64; ++e) {
    float qr[4], qi[4], kr[4], ki[4];
    #pragma unroll
    for (int i = 0; i < 4; ++i) { qr[i] = Qr[e][(ty << 2) + i]; qi[i] = Qi[e][(ty << 2) + i]; }
    #pragma unroll
    for (int j = 0; j < 4; ++j) { kr[j] = Kr[e][(tx << 2) + j]; ki[j] = Ki[e][(tx << 2) + j]; }
    #pragma unroll
    for (int i = 0; i < 4; ++i)
      #pragma unroll
      for (int j = 0; j < 4; ++j) {
        ar[i][j] += qr[i] * kr[j] - qi[i] * ki[j];
        ai[i][j] += qr[i] * ki[j] + qi[i] * kr[j];
      }
  }
  float* sp = Sout + (size_t)bh * 4096 * 2;
  #pragma unroll
  for (int i = 0; i < 4; ++i)
    #pragma unroll
    for (int j = 0; j < 4; ++j) {
      int x = (ty << 2) + i, y = (tx << 2) + j;
      float a = ar[i][j], bb = ai[i][j];
      float th = tanhf(a);
      float u = tanf(bb);
      float re, im;
      if (fabsf(u) <= 1.0f) {
        float dn = 1.0f + th * th * u * u;
        re = th * (1.0f + u * u) / dn;
        im = u * (1.0f - th * th) / dn;
      } else {
        float iu = 1.0f / u;
        float dn = iu * iu + th * th;
        re = th * (iu * iu + 1.0f) / dn;
        im = iu * (1.0f - th * th) / dn;
      }
      sp[(x * 64 + y) * 2]     = re;
      sp[(x * 64 + y) * 2 + 1] = im;
    }
}

// ---------------- cross: o[e,x] = sum_y s[x,y]*kf[e,y] ----------------
__global__ void k_cross_o(const float* __restrict__ Sin, const float* __restrict__ Sk,
                          float* __restrict__ O2) {
  int bh = blockIdx.x;
  int b = bh >> 3, h = bh & 7;
  __shared__ float SrT[64][64], SiT[64][64], KrT[64][64], KiT[64][64];
  int t = threadIdx.x;
  const float* sp = Sin + (size_t)bh * 8192;
  const float* kb = Sk + ((size_t)b * Dm + h * NE) * 128;
  for (int idx = t; idx < 4096; idx += 256) {
    int r = idx >> 6, c = idx & 63;
    SrT[c][r] = sp[idx * 2];
    SiT[c][r] = sp[idx * 2 + 1];
    KrT[c][r] = kb[r * 128 + c];
    KiT[c][r] = kb[r * 128 + 64 + c];
  }
  __syncthreads();
  int tx = t & 15, ty = t >> 4;
  float ar[4][4] = {}, ai[4][4] = {};
  for (int y = 0; y < 64; ++y) {
    float kr[4], ki[4], sr[4], si[4];
    #pragma unroll
    for (int i = 0; i < 4; ++i) { kr[i] = KrT[y][(ty << 2) + i]; ki[i] = KiT[y][(ty << 2) + i]; }
    #pragma unroll
    for (int j = 0; j < 4; ++j) { sr[j] = SrT[y][(tx << 2) + j]; si[j] = SiT[y][(tx << 2) + j]; }
    #pragma unroll
    for (int i = 0; i < 4; ++i)
      #pragma unroll
      for (int j = 0; j < 4; ++j) {
        ar[i][j] += sr[j] * kr[i] - si[j] * ki[i];
        ai[i][j] += sr[j] * ki[i] + si[j] * kr[i];
      }
  }
  float* ob = O2 + ((size_t)b * Dm + h * NE) * 128;
  #pragma unroll
  for (int i = 0; i < 4; ++i)
    #pragma unroll
    for (int j = 0; j < 4; ++j) {
      int e = (ty << 2) + i, x = (tx << 2) + j;
      ob[e * 128 + x]      = ar[i][j];
      ob[e * 128 + 64 + x] = ai[i][j];
    }
}

// ---------------- series_decomp: seasonal = z - MA25(z); trend write/add ----------------
template<int TMODE> // 0 none, 1 write trend, 2 add trend
__global__ void k_decomp(const float* __restrict__ Z, float* __restrict__ Sout,
                         float* __restrict__ T) {
  size_t idx = (size_t)blockIdx.x * 256 + threadIdx.x;
  int l = (int)((idx >> 9) & (L - 1));
  int b = (int)(idx >> 21);
  int d = (int)(idx & (Dm - 1));
  const float* zb = Z + ((size_t)b * L) * Dm + d;
  float s = 0.f;
  #pragma unroll
  for (int j = -12; j <= 12; ++j) {
    int ll = l + j; ll = ll < 0 ? 0 : (ll > L - 1 ? L - 1 : ll);
    s += zb[(size_t)ll * Dm];
  }
  float ma = s * (1.0f / 25.0f);
  Sout[idx] = Z[idx] - ma;
  if (TMODE == 1) T[idx] = ma;
  else if (TMODE == 2) T[idx] += ma;
}

// ---------------- row LayerNorm over Dm ----------------
__global__ void k_ln(const float* __restrict__ X, const float* __restrict__ g,
                     const float* __restrict__ be, float* __restrict__ Y) {
  int row = blockIdx.x;
  const float* x = X + (size_t)row * Dm;
  int t = threadIdx.x;
  float v0 = x[t], v1 = x[t + 256];
  float s = v0 + v1;
  __shared__ float red[4];
  #pragma unroll
  for (int off = 32; off > 0; off >>= 1) s += __shfl_down(s, off);
  int wid = t >> 6, lane = t & 63;
  if (lane == 0) red[wid] = s;
  __syncthreads();
  float mu = (red[0] + red[1] + red[2] + red[3]) * (1.0f / Dm);
  float e0 = v0 - mu, e1 = v1 - mu;
  float s2 = e0 * e0 + e1 * e1;
  #pragma unroll
  for (int off = 32; off > 0; off >>= 1) s2 += __shfl_down(s2, off);
  __syncthreads();
  if (lane == 0) red[wid] = s2;
  __syncthreads();
  float var = (red[0] + red[1] + red[2] + red[3]) * (1.0f / Dm);
  float rstd = rsqrtf(var + 1e-5f);
  float* y = Y + (size_t)row * Dm;
  y[t]       = e0 * rstd * g[t] + be[t];
  y[t + 256] = e1 * rstd * g[t + 256] + be[t + 256];
}

// ---------------- column sums over time (for my_layernorm mean) ----------------
__global__ void k_colsum(const float* __restrict__ X, float* __restrict__ cm) {
  int b = blockIdx.x;
  int d = blockIdx.y * 256 + threadIdx.x;
  int lc = blockIdx.z;
  const float* x = X + ((size_t)b * L + (size_t)lc * 128) * Dm + d;
  float s = 0.f;
  for (int i = 0; i < 128; ++i) s += x[(size_t)i * Dm];
  atomicAdd(&cm[b * Dm + d], s);
}

__global__ void k_sub(const float* __restrict__ X, const float* __restrict__ cm,
                      float* __restrict__ Y) {
  size_t idx = (size_t)blockIdx.x * 256 + threadIdx.x;
  int d = (int)(idx & (Dm - 1));
  int b = (int)(idx >> 21);
  Y[idx] = X[idx] - cm[b * Dm + d] * (1.0f / L);
}

// ---------------- trend projection: circular conv3 (Dm -> NF) ----------------
__global__ void k_trendproj(const float* __restrict__ T, const float* __restrict__ Wp,
                            float* __restrict__ RT) {
  int bl = blockIdx.x;
  int b = bl >> 12, l = bl & (L - 1);
  __shared__ float rows[3][512];
  __shared__ float partial[NF][13];
  int t = threadIdx.x;
  int lm = (l - 1) & (L - 1), lp = (l + 1) & (L - 1);
  const float* Tb = T + (size_t)b * L * Dm;
  for (int i = t; i < 512; i += 256) {
    rows[0][i] = Tb[(size_t)lm * Dm + i];
    rows[1][i] = Tb[(size_t)l  * Dm + i];
    rows[2][i] = Tb[(size_t)lp * Dm + i];
  }
  __syncthreads();
  if (t < 252) {
    int f = t / 12, p = t % 12;
    const float* w = Wp + (size_t)f * 1536 + p * 128;
    float s = 0.f;
    for (int q = 0; q < 128; ++q) {
      int k = p * 128 + q;
      int d = k / 3, j = k - d * 3;
      s += rows[j][d] * w[q];
    }
    partial[f][p] = s;
  }
  __syncthreads();
  if (t < NF) {
    float s = 0.f;
    #pragma unroll
    for (int p = 0; p < 12; ++p) s += partial[t][p];
    RT[((size_t)b * L + l) * NF + t] = s;
  }
}

// ---------------- final: out = tinit + RT + my_ln(x) @ Wf^T + bf, last PRED rows ----------------
__global__ void k_final(const float* __restrict__ X, const float* __restrict__ cm,
                        const float* __restrict__ Wf, const float* __restrict__ bf,
                        const float* __restrict__ tinit, const float* __restrict__ RT,
                        float* __restrict__ out) {
  int bt = blockIdx.x; int b = bt / PRED, tt = bt % PRED;
  int l = LABEL + tt;
  __shared__ float row[512];
  __shared__ float partial[NF][9];
  int t = threadIdx.x;
  const float* x = X + ((size_t)b * L + l) * Dm;
  const float* c = cm + b * Dm;
  row[t]       = x[t]       - c[t]       * (1.0f / L);
  row[t + 256] = x[t + 256] - c[t + 256] * (1.0f / L);
  __syncthreads();
  if (t < 168) {
    int f = t >> 3, p = t & 7;
    const float* w = Wf + (size_t)f * Dm + p * 64;
    float s = 0.f;
    #pragma unroll
    for (int q = 0; q < 64; ++q) s += row[p * 64 + q] * w[q];
    partial[f][p] = s;
  }
  __syncthreads();
  if (t < NF) {
    float s = bf[t];
    #pragma unroll
    for (int p = 0; p < 8; ++p) s += partial[t][p];
    size_t src = ((size_t)b * L + l) * NF + t;
    out[((size_t)b * PRED + tt) * NF + t] = s + tinit[src] + RT[src];
  }
}

} // namespace

extern "C" void kernel_launch(void* const* d_in, const int* in_sizes, int n_in,
                              void* d_out, int out_size, void* d_ws, size_t ws_size,
                              hipStream_t stream) {
  (void)in_sizes; (void)n_in; (void)out_size; (void)ws_size;
  const float* x_enc              = (const float*)d_in[0];
  const float* enc_emb_W          = (const float*)d_in[3];
  const float* dec_emb_W          = (const float*)d_in[4];
  const float* enc_qkvo_W         = (const float*)d_in[5];
  const float* enc_qkvo_b         = (const float*)d_in[6];
  const float* enc_ffn_W1         = (const float*)d_in[7];
  const float* enc_ffn_W2         = (const float*)d_in[8];
  const float* enc_fourier_W      = (const float*)d_in[9];
  const float* enc_norm_g         = (const float*)d_in[10];
  const float* enc_norm_b         = (const float*)d_in[11];
  const float* dec_qkvo_W         = (const float*)d_in[12];
  const float* dec_qkvo_b         = (const float*)d_in[13];
  const float* dec_ffn_W1         = (const float*)d_in[14];
  const float* dec_ffn_W2         = (const float*)d_in[15];
  const float* dec_self_fourier_W = (const float*)d_in[16];
  const float* dec_cross_fourier_W= (const float*)d_in[17];
  const float* dec_trend_proj_W   = (const float*)d_in[18];
  const float* dec_norm_g         = (const float*)d_in[19];
  const float* dec_norm_b         = (const float*)d_in[20];
  const float* final_W            = (const float*)d_in[21];
  const float* final_b            = (const float*)d_in[22];
  float* out = (float*)d_out;

  float* ws = (float*)d_ws;
  const size_t SZ = (size_t)NB * L * Dm;  // 8,388,608 floats
  float* S_enc = ws;
  float* S_dec = ws + SZ;
  float* S_q   = ws + 2 * SZ;   // also FFN hidden chunk (4096x2048 == SZ)
  float* S_i   = ws + 3 * SZ;
  float* S_z   = ws + 4 * SZ;
  float* S_x1  = ws + 5 * SZ;
  float* T_sum = ws + 6 * SZ;
  float* sm = ws + 7 * SZ;
  float* spec_q  = sm; sm += 262144;
  float* spec_k  = sm; sm += 262144;
  float* spec_o  = sm; sm += 262144;
  float* spec_o2 = sm; sm += 262144;
  float* spec_s  = sm; sm += 524288;
  float* mean_bf = sm; sm += 128;
  float* cm      = sm; sm += 2048;
  float* sinit   = sm; sm += (size_t)NB * L * NF;
  float* tinit   = sm; sm += (size_t)NB * L * NF;
  float* RT      = sm; sm += (size_t)NB * L * NF;

  enum { MODE_BIAS, MODE_BIAS_RES, MODE_GELU, MODE_RES };
  auto gemm = [&](const float* A, const float* W, const float* bias, const float* R,
                  float* C, int Mr, int N, int K, int mode) {
    dim3 grid((unsigned)((Mr >> 6) * (N >> 6)));
    if (mode == MODE_BIAS)
      k_gemm<true, false, false><<<grid, 256, 0, stream>>>(A, W, bias, nullptr, C, N, K);
    else if (mode == MODE_BIAS_RES)
      k_gemm<true, true, false><<<grid, 256, 0, stream>>>(A, W, bias, R, C, N, K);
    else if (mode == MODE_GELU)
      k_gemm<false, false, true><<<grid, 256, 0, stream>>>(A, W, nullptr, nullptr, C, N, K);
    else
      k_gemm<false, true, false><<<grid, 256, 0, stream>>>(A, W, nullptr, R, C, N, K);
  };
  auto dft = [&](const float* A, float* S) {
    hipMemsetAsync(S, 0, 262144 * sizeof(float), stream);
    k_dft<<<dim3(16, 8, NB), 256, 0, stream>>>(A, S);
  };

  const int MR = NB * L;        // 16384 rows
  const size_t CH = (size_t)4096 * Dm; // chunk stride for FFN

  // ---- Phase A: init + embeddings ----
  k_enc_mean<<<NB * NF, 256, 0, stream>>>(x_enc, mean_bf);
  k_init_decomp<<<(NB * L * NF + 255) / 256, 256, 0, stream>>>(x_enc, mean_bf, sinit, tinit);
  k_embed<<<NB * L, 256, 0, stream>>>(x_enc, enc_emb_W, S_enc);

  // ---- Phase B: encoder x2 (shared Fourier weights) ----
  for (int layer = 0; layer < 2; ++layer) {
    const float* Wl = enc_qkvo_W + (size_t)layer * 4 * Dm * Dm;
    const float* bl = enc_qkvo_b + (size_t)layer * 4 * Dm;
    gemm(S_enc, Wl, bl, nullptr, S_q, MR, Dm, Dm, MODE_BIAS);            // q proj
    dft(S_q, spec_q);
    k_cmul<<<NB * NH * NM, 64, 0, stream>>>(spec_q, enc_fourier_W, spec_o);
    k_irdft<<<dim3(64, 8, NB), 256, 0, stream>>>(spec_o, S_i, 1.0f / L);
    gemm(S_i, Wl + 3 * Dm * Dm, bl + 3 * Dm, S_enc, S_z, MR, Dm, Dm, MODE_BIAS_RES); // out proj + res
    k_decomp<0><<<32768, 256, 0, stream>>>(S_z, S_x1, nullptr);
    for (int ch = 0; ch < 4; ++ch) {
      gemm(S_x1 + ch * CH, enc_ffn_W1 + (size_t)layer * DFF * Dm, nullptr, nullptr,
           S_q, 4096, DFF, Dm, MODE_GELU);
      gemm(S_q, enc_ffn_W2 + (size_t)layer * Dm * DFF, nullptr, S_x1 + ch * CH,
           S_z + ch * CH, 4096, Dm, DFF, MODE_RES);
    }
    k_decomp<0><<<32768, 256, 0, stream>>>(S_z, S_enc, nullptr);
  }
  // my_layernorm(enc_out)
  k_ln<<<NB * L, 256, 0, stream>>>(S_enc, enc_norm_g, enc_norm_b, S_z);
  hipMemsetAsync(cm, 0, 2048 * sizeof(float), stream);
  k_colsum<<<dim3(NB, 2, 32), 256, 0, stream>>>(S_z, cm);
  k_sub<<<32768, 256, 0, stream>>>(S_z, cm, S_enc);

  // ---- Phase C: decoder ----
  k_embed<<<NB * L, 256, 0, stream>>>(sinit, dec_emb_W, S_dec);
  // self attention
  {
    const float* Wl = dec_qkvo_W;
    const float* bl = dec_qkvo_b;
    gemm(S_dec, Wl, bl, nullptr, S_q, MR, Dm, Dm, MODE_BIAS);
    dft(S_q, spec_q);
    k_cmul<<<NB * NH * NM, 64, 0, stream>>>(spec_q, dec_self_fourier_W, spec_o);
    k_irdft<<<dim3(64, 8, NB), 256, 0, stream>>>(spec_o, S_i, 1.0f / L);
    gemm(S_i, Wl + 3 * Dm * Dm, bl + 3 * Dm, S_dec, S_z, MR, Dm, Dm, MODE_BIAS_RES);
    k_decomp<1><<<32768, 256, 0, stream>>>(S_z, S_x1, T_sum);
  }
  // cross attention
  {
    const float* Wl = dec_qkvo_W + (size_t)4 * Dm * Dm;
    const float* bl = dec_qkvo_b + 4 * Dm;
    gemm(S_x1, Wl, bl, nullptr, S_q, MR, Dm, Dm, MODE_BIAS);                       // q
    gemm(S_enc, Wl + Dm * Dm, bl + Dm, nullptr, S_i, MR, Dm, Dm, MODE_BIAS);       // k
    dft(S_q, spec_q);
    dft(S_i, spec_k);
    k_cross_s<<<NB * NH, 256, 0, stream>>>(spec_q, spec_k, spec_s);
    k_cross_o<<<NB * NH, 256, 0, stream>>>(spec_s, spec_k, spec_o2);
    k_cmul<<<NB * NH * NM, 64, 0, stream>>>(spec_o2, dec_cross_fourier_W, spec_o);
    k_irdft<<<dim3(64, 8, NB), 256, 0, stream>>>(spec_o, S_i,
                                                 (1.0f / L) / (512.0f * 512.0f));
    gemm(S_i, Wl + 3 * Dm * Dm, bl + 3 * Dm, S_x1, S_z, MR, Dm, Dm, MODE_BIAS_RES);
    k_decomp<2><<<32768, 256, 0, stream>>>(S_z, S_dec, T_sum);
  }
  // ffn
  for (int ch = 0; ch < 4; ++ch) {
    gemm(S_dec + ch * CH, dec_ffn_W1, nullptr, nullptr, S_q, 4096, DFF, Dm, MODE_GELU);
    gemm(S_q, dec_ffn_W2, nullptr, S_dec + ch * CH, S_z + ch * CH, 4096, Dm, DFF, MODE_RES);
  }
  k_decomp<2><<<32768, 256, 0, stream>>>(S_z, S_x1, T_sum);
  // trend projection + final
  k_trendproj<<<NB * L, 256, 0, stream>>>(T_sum, dec_trend_proj_W, RT);
  k_ln<<<NB * L, 256, 0, stream>>>(S_x1, dec_norm_g, dec_norm_b, S_z);
  hipMemsetAsync(cm, 0, 2048 * sizeof(float), stream);
  k_colsum<<<dim3(NB, 2, 32), 256, 0, stream>>>(S_z, cm);
  k_final<<<NB * PRED, 256, 0, stream>>>(S_z, cm, final_W, final_b, tinit, RT, out);
}

// Round 3
// 2963.973 us; speedup vs baseline: 2.1756x; 2.1756x over previous
//
#include <hip/hip_runtime.h>
#include <hip/hip_bf16.h>
#include <math.h>

namespace {

constexpr int NB    = 4;
constexpr int L     = 4096;   // SEQ == LDEC
constexpr int PRED  = 2048;
constexpr int LABEL = 2048;
constexpr int NF    = 21;
constexpr int Dm    = 512;
constexpr int NH    = 8;
constexpr int NE    = 64;
constexpr int NM    = 64;
constexpr int DFF   = 2048;
constexpr float TWOPI = 6.283185307179586f;

typedef __attribute__((ext_vector_type(8))) short s16x8;
typedef __attribute__((ext_vector_type(4))) float f32x4;

__device__ inline short f2b(float f) {
  __hip_bfloat16 h = __float2bfloat16(f);
  return __builtin_bit_cast(short, h);
}

// ---------------- init: column mean of x_enc over time ----------------
__global__ void k_enc_mean(const float* __restrict__ x, float* __restrict__ mean_bf) {
  int bf = blockIdx.x; int b = bf / NF, f = bf % NF;
  const float* p = x + (size_t)b * L * NF + f;
  float s = 0.f;
  for (int l = threadIdx.x; l < L; l += 256) s += p[(size_t)l * NF];
  __shared__ float red[256];
  red[threadIdx.x] = s; __syncthreads();
  for (int st = 128; st > 0; st >>= 1) {
    if (threadIdx.x < st) red[threadIdx.x] += red[threadIdx.x + st];
    __syncthreads();
  }
  if (threadIdx.x == 0) mean_bf[bf] = red[0] * (1.0f / L);
}

// ---------------- init decomp: seasonal_init / trend_init ----------------
__global__ void k_init_decomp(const float* __restrict__ x, const float* __restrict__ mean_bf,
                              float* __restrict__ sinit, float* __restrict__ tinit) {
  int idx = blockIdx.x * 256 + threadIdx.x;
  if (idx >= NB * L * NF) return;
  int f = idx % NF; int t = (idx / NF) % L; int b = idx / (NF * L);
  float sv, tv;
  if (t < LABEL) {
    int l = LABEL + t;
    float s = 0.f;
    #pragma unroll
    for (int j = -12; j <= 12; ++j) {
      int ll = l + j; ll = ll < 0 ? 0 : (ll > L - 1 ? L - 1 : ll);
      s += x[((size_t)b * L + ll) * NF + f];
    }
    float ma = s * (1.0f / 25.0f);
    sv = x[((size_t)b * L + l) * NF + f] - ma;
    tv = ma;
  } else { sv = 0.f; tv = mean_bf[b * NF + f]; }
  sinit[idx] = sv; tinit[idx] = tv;
}

// ---------------- embedding: circular conv3 (NF->Dm) + positional, tiled ----------------
// block: 64 l x 64 d tile; W panel staged in LDS once per block.
__global__ __launch_bounds__(256) void k_embed2(const float* __restrict__ x,
                                                const float* __restrict__ W,
                                                float* __restrict__ out) {
  int bid = blockIdx.x;
  int dt = bid & 7;
  int lt = (bid >> 3) & 63;
  int b  = bid >> 9;
  int l0 = lt << 6, d0 = dt << 6;
  __shared__ float xs[66][22];
  __shared__ float wt[63][68];
  int t = threadIdx.x;
  for (int i = t; i < 66 * 21; i += 256) {
    int r = i / 21, f = i - r * 21;
    int l = (l0 - 1 + r) & (L - 1);
    xs[r][f] = x[((size_t)b * L + l) * NF + f];
  }
  for (int i = t; i < 63 * 64; i += 256) {
    int k = i >> 6, dd = i & 63;
    wt[k][dd] = W[(size_t)(d0 + dd) * 63 + k];
  }
  __syncthreads();
  int tx = t & 15, ty = t >> 4;
  float acc[4][4] = {};
  #pragma unroll
  for (int f = 0; f < 21; ++f) {
    #pragma unroll
    for (int j = 0; j < 3; ++j) {
      int k = f * 3 + j;
      float xv[4], wv[4];
      #pragma unroll
      for (int i = 0; i < 4; ++i) xv[i] = xs[ty * 4 + i + j][f];
      #pragma unroll
      for (int jj = 0; jj < 4; ++jj) wv[jj] = wt[k][tx * 4 + jj];
      #pragma unroll
      for (int i = 0; i < 4; ++i)
        #pragma unroll
        for (int jj = 0; jj < 4; ++jj) acc[i][jj] += xv[i] * wv[jj];
    }
  }
  #pragma unroll
  for (int i = 0; i < 4; ++i) {
    int l = l0 + ty * 4 + i;
    #pragma unroll
    for (int jj = 0; jj < 4; ++jj) {
      int d = d0 + tx * 4 + jj;
      float dv = expf((float)(d & ~1) * (-9.210340371976184f / 512.0f));
      float ang = (float)l * dv;
      float pe = (d & 1) ? cosf(ang) : sinf(ang);
      out[((size_t)b * L + l) * Dm + d] = acc[i][jj] + pe;
    }
  }
}

// ---------------- bf16 MFMA GEMM: C = A @ W^T (+bias)(+gelu)(+res), fp32 in/out ----------------
// 128x128 tile, BK=64, 256 threads (4 waves, 2x2 wave grid, 4x4 16x16 frags each).
// fp32 global -> reg -> bf16 cvt -> XOR-swizzled LDS -> mfma_f32_16x16x32_bf16.
template<bool BIAS, bool RES, bool GELU>
__global__ __launch_bounds__(256) void k_bgemm(const float* __restrict__ A, const float* __restrict__ W,
                       const float* __restrict__ bias, const float* __restrict__ R,
                       float* __restrict__ C, int N, int K) {
  __shared__ __align__(16) short As[128 * 64];
  __shared__ __align__(16) short Bs[128 * 64];
  int nt = N >> 7;
  int n0 = (blockIdx.x % nt) << 7;
  int m0 = (int)(blockIdx.x / nt) << 7;
  int t = threadIdx.x;
  int row = t >> 1;
  int kh = (t & 1) << 5;          // 0 or 32 floats
  const float* Ap = A + (size_t)(m0 + row) * K + kh;
  const float* Wp = W + (size_t)(n0 + row) * K + kh;
  int wbase = row * 128 + (t & 1) * 64;
  int swz = (row & 7) << 4;
  int lane = t & 63, w = t >> 6;
  int wr = (w >> 1) << 6, wc = (w & 1) << 6;
  int fr_a = wr + (lane & 15);
  int fr_b = wc + (lane & 15);
  int kg = (lane >> 4) << 4;      // byte offset of k-group within 64B half
  f32x4 ra[8], rb[8];
  f32x4 acc[4][4] = {};

  #pragma unroll
  for (int q = 0; q < 8; ++q) {
    ra[q] = *(const f32x4*)(Ap + q * 4);
    rb[q] = *(const f32x4*)(Wp + q * 4);
  }
  for (int k0 = 0; k0 < K; k0 += 64) {
    if (k0) __syncthreads();
    #pragma unroll
    for (int h = 0; h < 4; ++h) {
      s16x8 va, vb;
      #pragma unroll
      for (int e = 0; e < 8; ++e) {
        va[e] = f2b(ra[h * 2 + (e >> 2)][e & 3]);
        vb[e] = f2b(rb[h * 2 + (e >> 2)][e & 3]);
      }
      int wb = (wbase + h * 16) ^ swz;
      *(s16x8*)((char*)As + wb) = va;
      *(s16x8*)((char*)Bs + wb) = vb;
    }
    __syncthreads();
    if (k0 + 64 < K) {
      #pragma unroll
      for (int q = 0; q < 8; ++q) {
        ra[q] = *(const f32x4*)(Ap + k0 + 64 + q * 4);
        rb[q] = *(const f32x4*)(Wp + k0 + 64 + q * 4);
      }
    }
    #pragma unroll
    for (int ks = 0; ks < 2; ++ks) {
      s16x8 af[4], bfr[4];
      #pragma unroll
      for (int f = 0; f < 4; ++f) {
        int r1 = fr_a + f * 16;
        af[f] = *(const s16x8*)((const char*)As + ((r1 * 128 + ks * 64 + kg) ^ ((r1 & 7) << 4)));
        int r2 = fr_b + f * 16;
        bfr[f] = *(const s16x8*)((const char*)Bs + ((r2 * 128 + ks * 64 + kg) ^ ((r2 & 7) << 4)));
      }
      #pragma unroll
      for (int fm = 0; fm < 4; ++fm)
        #pragma unroll
        for (int fn = 0; fn < 4; ++fn)
          acc[fm][fn] = __builtin_amdgcn_mfma_f32_16x16x32_bf16(af[fm], bfr[fn], acc[fm][fn], 0, 0, 0);
    }
  }
  int em = m0 + wr + (lane >> 4) * 4;
  int en = n0 + wc + (lane & 15);
  #pragma unroll
  for (int fm = 0; fm < 4; ++fm) {
    #pragma unroll
    for (int fn = 0; fn < 4; ++fn) {
      int n = en + fn * 16;
      #pragma unroll
      for (int r = 0; r < 4; ++r) {
        int m = em + fm * 16 + r;
        float v = acc[fm][fn][r];
        if (BIAS) v += bias[n];
        if (GELU) v = 0.5f * v * (1.0f + erff(v * 0.70710678118654752f));
        if (RES)  v += R[(size_t)m * N + n];
        C[(size_t)m * N + n] = v;
      }
    }
  }
}

// ---------------- forward DFT (first 64 bins): S[b,c,0..63]=Re, [64..127]=Im ----------------
__global__ void k_dft(const float* __restrict__ A, float* __restrict__ S) {
  int mt = blockIdx.x & 1, seg = blockIdx.x >> 1;
  int c0 = blockIdx.y << 6;
  int b  = blockIdx.z;
  int m0 = mt << 6;
  __shared__ float As[16][68];
  __shared__ float Fs[16][68];
  int t = threadIdx.x, tx = t & 15, ty = t >> 4;
  int rr = t >> 6, cc = t & 63;
  float acc[4][4] = {};
  const float* Ab = A + (size_t)b * L * Dm;
  int lbeg = seg * (L / 8);
  for (int l0 = lbeg; l0 < lbeg + L / 8; l0 += 16) {
    #pragma unroll
    for (int q = 0; q < 4; ++q) {
      int lr = rr + q * 4;
      As[lr][cc] = Ab[(size_t)(l0 + lr) * Dm + c0 + cc];
      int m2 = m0 + cc;
      int m = m2 & 63;
      int ph = (m * (l0 + lr)) & (L - 1);
      float sv, cv;
      __sincosf((float)ph * (TWOPI / L), &sv, &cv);
      Fs[lr][cc] = (m2 < 64) ? cv : -sv;
    }
    __syncthreads();
    #pragma unroll
    for (int k = 0; k < 16; ++k) {
      float av[4], fv[4];
      #pragma unroll
      for (int i = 0; i < 4; ++i) av[i] = As[k][(ty << 2) + i];
      #pragma unroll
      for (int j = 0; j < 4; ++j) fv[j] = Fs[k][(tx << 2) + j];
      #pragma unroll
      for (int i = 0; i < 4; ++i)
        #pragma unroll
        for (int j = 0; j < 4; ++j) acc[i][j] += av[i] * fv[j];
    }
    __syncthreads();
  }
  #pragma unroll
  for (int i = 0; i < 4; ++i) {
    int c = c0 + (ty << 2) + i;
    #pragma unroll
    for (int j = 0; j < 4; ++j) {
      int m2 = m0 + (tx << 2) + j;
      atomicAdd(&S[((size_t)b * Dm + c) * 128 + m2], acc[i][j]);
    }
  }
}

// ---------------- inverse DFT (64 nonzero bins, numpy C2R: Im(bin0) dropped) ----------------
__global__ void k_irdft(const float* __restrict__ S, float* __restrict__ O, float scale) {
  int l0 = blockIdx.x << 6;
  int c0 = blockIdx.y << 6;
  int b  = blockIdx.z;
  __shared__ float Ss[16][68];
  __shared__ float Gs[16][68];
  int t = threadIdx.x, tx = t & 15, ty = t >> 4;
  int rr = t >> 6, cc = t & 63;
  float acc[4][4] = {};
  for (int m0 = 0; m0 < 128; m0 += 16) {
    #pragma unroll
    for (int q = 0; q < 4; ++q) {
      int kr = rr + q * 4;
      Ss[kr][cc] = S[((size_t)b * Dm + c0 + cc) * 128 + m0 + kr];
      int m2 = m0 + kr;
      int l = l0 + cc;
      float g;
      if (m2 == 0) g = 1.0f;
      else if (m2 == 64) g = 0.0f;
      else {
        int m = m2 & 63;
        int ph = (m * l) & (L - 1);
        float sv, cv;
        __sincosf((float)ph * (TWOPI / L), &sv, &cv);
        g = (m2 < 64) ? 2.0f * cv : -2.0f * sv;
      }
      Gs[kr][cc] = g;
    }
    __syncthreads();
    #pragma unroll
    for (int k = 0; k < 16; ++k) {
      float av[4], gv[4];
      #pragma unroll
      for (int i = 0; i < 4; ++i) av[i] = Ss[k][(ty << 2) + i];
      #pragma unroll
      for (int j = 0; j < 4; ++j) gv[j] = Gs[k][(tx << 2) + j];
      #pragma unroll
      for (int i = 0; i < 4; ++i)
        #pragma unroll
        for (int j = 0; j < 4; ++j) acc[i][j] += av[i] * gv[j];
    }
    __syncthreads();
  }
  #pragma unroll
  for (int i = 0; i < 4; ++i) {
    int c = c0 + (ty << 2) + i;
    #pragma unroll
    for (int j = 0; j < 4; ++j) {
      int l = l0 + (tx << 2) + j;
      O[((size_t)b * Dm + c) * L + l] = acc[i][j] * scale;
    }
  }
}

// ---------------- per-mode complex channel mix ----------------
__global__ void k_cmul(const float* __restrict__ S, const float* __restrict__ Wf,
                       float* __restrict__ O) {
  int blk = blockIdx.x;
  int m = blk & 63;
  int h = (blk >> 6) & 7;
  int b = blk >> 9;
  int o = threadIdx.x;
  const float* Sb = S + ((size_t)b * Dm + h * NE) * 128;
  const float* Wb = Wf + (size_t)h * NE * NE * NM * 2;
  float ar = 0.f, ai = 0.f;
  for (int i = 0; i < NE; ++i) {
    float qr = Sb[i * 128 + m], qi = Sb[i * 128 + 64 + m];
    const float* w = Wb + (((size_t)i * NE + o) * NM + m) * 2;
    float wr = w[0], wi = w[1];
    ar += qr * wr - qi * wi;
    ai += qr * wi + qi * wr;
  }
  float* Ob = O + ((size_t)b * Dm + h * NE) * 128;
  Ob[o * 128 + m] = ar;
  Ob[o * 128 + 64 + m] = ai;
}

// ---------------- cross: s[x,y] = ctanh(sum_e qf[e,x]*kf[e,y]) ----------------
__global__ void k_cross_s(const float* __restrict__ Sq, const float* __restrict__ Sk,
                          float* __restrict__ Sout) {
  int bh = blockIdx.x;
  int b = bh >> 3, h = bh & 7;
  __shared__ float Qr[64][64], Qi[64][64], Kr[64][64], Ki[64][64];
  int t = threadIdx.x;
  const float* qb = Sq + ((size_t)b * Dm + h * NE) * 128;
  const float* kb = Sk + ((size_t)b * Dm + h * NE) * 128;
  for (int idx = t; idx < 4096; idx += 256) {
    int e = idx >> 6, x = idx & 63;
    Qr[e][x] = qb[e * 128 + x];
    Qi[e][x] = qb[e * 128 + 64 + x];
    Kr[e][x] = kb[e * 128 + x];
    Ki[e][x] = kb[e * 128 + 64 + x];
  }
  __syncthreads();
  int tx = t & 15, ty = t >> 4;
  float ar[4][4] = {}, ai[4][4] = {};
  for (int e = 0; e < 64; ++e) {
    float qr[4], qi[4], kr[4], ki[4];
    #pragma unroll
    for (int i = 0; i < 4; ++i) { qr[i] = Qr[e][(ty << 2) + i]; qi[i] = Qi[e][(ty << 2) + i]; }
    #pragma unroll
    for (int j = 0; j < 4; ++j) { kr[j] = Kr[e][(tx << 2) + j]; ki[j] = Ki[e][(tx << 2) + j]; }
    #pragma unroll
    for (int i = 0; i < 4; ++i)
      #pragma unroll
      for (int j = 0; j < 4; ++j) {
        ar[i][j] += qr[i] * kr[j] - qi[i] * ki[j];
        ai[i][j] += qr[i] * ki[j] + qi[i] * kr[j];
      }
  }
  float* sp = Sout + (size_t)bh * 4096 * 2;
  #pragma unroll
  for (int i = 0; i < 4; ++i)
    #pragma unroll
    for (int j = 0; j < 4; ++j) {
      int x = (ty << 2) + i, y = (tx << 2) + j;
      float a = ar[i][j], bb = ai[i][j];
      float th = tanhf(a);
      float u = tanf(bb);
      float re, im;
      if (fabsf(u) <= 1.0f) {
        float dn = 1.0f + th * th * u * u;
        re = th * (1.0f + u * u) / dn;
        im = u * (1.0f - th * th) / dn;
      } else {
        float iu = 1.0f / u;
        float dn = iu * iu + th * th;
        re = th * (iu * iu + 1.0f) / dn;
        im = iu * (1.0f - th * th) / dn;
      }
      sp[(x * 64 + y) * 2]     = re;
      sp[(x * 64 + y) * 2 + 1] = im;
    }
}

// ---------------- cross: o[e,x] = sum_y s[x,y]*kf[e,y] ----------------
__global__ void k_cross_o(const float* __restrict__ Sin, const float* __restrict__ Sk,
                          float* __restrict__ O2) {
  int bh = blockIdx.x;
  int b = bh >> 3, h = bh & 7;
  __shared__ float SrT[64][64], SiT[64][64], KrT[64][64], KiT[64][64];
  int t = threadIdx.x;
  const float* sp = Sin + (size_t)bh * 8192;
  const float* kb = Sk + ((size_t)b * Dm + h * NE) * 128;
  for (int idx = t; idx < 4096; idx += 256) {
    int r = idx >> 6, c = idx & 63;
    SrT[c][r] = sp[idx * 2];
    SiT[c][r] = sp[idx * 2 + 1];
    KrT[c][r] = kb[r * 128 + c];
    KiT[c][r] = kb[r * 128 + 64 + c];
  }
  __syncthreads();
  int tx = t & 15, ty = t >> 4;
  float ar[4][4] = {}, ai[4][4] = {};
  for (int y = 0; y < 64; ++y) {
    float kr[4], ki[4], sr[4], si[4];
    #pragma unroll
    for (int i = 0; i < 4; ++i) { kr[i] = KrT[y][(ty << 2) + i]; ki[i] = KiT[y][(ty << 2) + i]; }
    #pragma unroll
    for (int j = 0; j < 4; ++j) { sr[j] = SrT[y][(tx << 2) + j]; si[j] = SiT[y][(tx << 2) + j]; }
    #pragma unroll
    for (int i = 0; i < 4; ++i)
      #pragma unroll
      for (int j = 0; j < 4; ++j) {
        ar[i][j] += sr[j] * kr[i] - si[j] * ki[i];
        ai[i][j] += sr[j] * ki[i] + si[j] * kr[i];
      }
  }
  float* ob = O2 + ((size_t)b * Dm + h * NE) * 128;
  #pragma unroll
  for (int i = 0; i < 4; ++i)
    #pragma unroll
    for (int j = 0; j < 4; ++j) {
      int e = (ty << 2) + i, x = (tx << 2) + j;
      ob[e * 128 + x]      = ar[i][j];
      ob[e * 128 + 64 + x] = ai[i][j];
    }
}

// ---------------- series_decomp (sliding window): seasonal = z - MA25(z) ----------------
template<int TMODE> // 0 none, 1 write trend, 2 add trend
__global__ __launch_bounds__(512) void k_decomp2(const float* __restrict__ Z, float* __restrict__ Sout,
                          float* __restrict__ T) {
  int b = blockIdx.x >> 6;
  int l0 = (blockIdx.x & 63) << 6;
  int d = threadIdx.x;
  const float* zb = Z + (size_t)b * L * Dm + d;
  float s = 0.f;
  #pragma unroll
  for (int j = -12; j <= 12; ++j) {
    int ll = l0 + j; ll = ll < 0 ? 0 : ll;
    s += zb[(size_t)ll * Dm];
  }
  for (int i = 0; i < 64; ++i) {
    int l = l0 + i;
    float ma = s * (1.0f / 25.0f);
    size_t idx = ((size_t)b * L + l) * Dm + d;
    Sout[idx] = zb[(size_t)l * Dm] - ma;
    if (TMODE == 1) T[idx] = ma;
    else if (TMODE == 2) T[idx] += ma;
    int la = l + 13; la = la > L - 1 ? L - 1 : la;
    int lr = l - 12; lr = lr < 0 ? 0 : lr;
    s += zb[(size_t)la * Dm] - zb[(size_t)lr * Dm];
  }
}

// ---------------- row LayerNorm over Dm ----------------
__global__ void k_ln(const float* __restrict__ X, const float* __restrict__ g,
                     const float* __restrict__ be, float* __restrict__ Y) {
  int row = blockIdx.x;
  const float* x = X + (size_t)row * Dm;
  int t = threadIdx.x;
  float v0 = x[t], v1 = x[t + 256];
  float s = v0 + v1;
  __shared__ float red[4];
  #pragma unroll
  for (int off = 32; off > 0; off >>= 1) s += __shfl_down(s, off);
  int wid = t >> 6, lane = t & 63;
  if (lane == 0) red[wid] = s;
  __syncthreads();
  float mu = (red[0] + red[1] + red[2] + red[3]) * (1.0f / Dm);
  float e0 = v0 - mu, e1 = v1 - mu;
  float s2 = e0 * e0 + e1 * e1;
  #pragma unroll
  for (int off = 32; off > 0; off >>= 1) s2 += __shfl_down(s2, off);
  __syncthreads();
  if (lane == 0) red[wid] = s2;
  __syncthreads();
  float var = (red[0] + red[1] + red[2] + red[3]) * (1.0f / Dm);
  float rstd = rsqrtf(var + 1e-5f);
  float* y = Y + (size_t)row * Dm;
  y[t]       = e0 * rstd * g[t] + be[t];
  y[t + 256] = e1 * rstd * g[t + 256] + be[t + 256];
}

// ---------------- column sums over time (for my_layernorm mean) ----------------
__global__ void k_colsum(const float* __restrict__ X, float* __restrict__ cm) {
  int b = blockIdx.x;
  int d = blockIdx.y * 256 + threadIdx.x;
  int lc = blockIdx.z;
  const float* x = X + ((size_t)b * L + (size_t)lc * 128) * Dm + d;
  float s = 0.f;
  for (int i = 0; i < 128; ++i) s += x[(size_t)i * Dm];
  atomicAdd(&cm[b * Dm + d], s);
}

__global__ void k_sub(const float* __restrict__ X, const float* __restrict__ cm,
                      float* __restrict__ Y) {
  size_t idx = (size_t)blockIdx.x * 256 + threadIdx.x;
  int d = (int)(idx & (Dm - 1));
  int b = (int)(idx >> 21);
  Y[idx] = X[idx] - cm[b * Dm + d] * (1.0f / L);
}

// ---------------- trend projection: circular conv3 (Dm -> NF) ----------------
__global__ void k_trendproj(const float* __restrict__ T, const float* __restrict__ Wp,
                            float* __restrict__ RT) {
  int bl = blockIdx.x;
  int b = bl >> 12, l = bl & (L - 1);
  __shared__ float rows[3][512];
  __shared__ float partial[NF][13];
  int t = threadIdx.x;
  int lm = (l - 1) & (L - 1), lp = (l + 1) & (L - 1);
  const float* Tb = T + (size_t)b * L * Dm;
  for (int i = t; i < 512; i += 256) {
    rows[0][i] = Tb[(size_t)lm * Dm + i];
    rows[1][i] = Tb[(size_t)l  * Dm + i];
    rows[2][i] = Tb[(size_t)lp * Dm + i];
  }
  __syncthreads();
  if (t < 252) {
    int f = t / 12, p = t % 12;
    const float* w = Wp + (size_t)f * 1536 + p * 128;
    float s = 0.f;
    for (int q = 0; q < 128; ++q) {
      int k = p * 128 + q;
      int d = k / 3, j = k - d * 3;
      s += rows[j][d] * w[q];
    }
    partial[f][p] = s;
  }
  __syncthreads();
  if (t < NF) {
    float s = 0.f;
    #pragma unroll
    for (int p = 0; p < 12; ++p) s += partial[t][p];
    RT[((size_t)b * L + l) * NF + t] = s;
  }
}

// ---------------- final: out = tinit + RT + my_ln(x) @ Wf^T + bf ----------------
__global__ void k_final(const float* __restrict__ X, const float* __restrict__ cm,
                        const float* __restrict__ Wf, const float* __restrict__ bf,
                        const float* __restrict__ tinit, const float* __restrict__ RT,
                        float* __restrict__ out) {
  int bt = blockIdx.x; int b = bt / PRED, tt = bt % PRED;
  int l = LABEL + tt;
  __shared__ float row[512];
  __shared__ float partial[NF][9];
  int t = threadIdx.x;
  const float* x = X + ((size_t)b * L + l) * Dm;
  const float* c = cm + b * Dm;
  row[t]       = x[t]       - c[t]       * (1.0f / L);
  row[t + 256] = x[t + 256] - c[t + 256] * (1.0f / L);
  __syncthreads();
  if (t < 168) {
    int f = t >> 3, p = t & 7;
    const float* w = Wf + (size_t)f * Dm + p * 64;
    float s = 0.f;
    #pragma unroll
    for (int q = 0; q < 64; ++q) s += row[p * 64 + q] * w[q];
    partial[f][p] = s;
  }
  __syncthreads();
  if (t < NF) {
    float s = bf[t];
    #pragma unroll
    for (int p = 0; p < 8; ++p) s += partial[t][p];
    size_t src = ((size_t)b * L + l) * NF + t;
    out[((size_t)b * PRED + tt) * NF + t] = s + tinit[src] + RT[src];
  }
}

} // namespace

extern "C" void kernel_launch(void* const* d_in, const int* in_sizes, int n_in,
                              void* d_out, int out_size, void* d_ws, size_t ws_size,
                              hipStream_t stream) {
  (void)in_sizes; (void)n_in; (void)out_size; (void)ws_size;
  const float* x_enc              = (const float*)d_in[0];
  const float* enc_emb_W          = (const float*)d_in[3];
  const float* dec_emb_W          = (const float*)d_in[4];
  const float* enc_qkvo_W         = (const float*)d_in[5];
  const float* enc_qkvo_b         = (const float*)d_in[6];
  const float* enc_ffn_W1         = (const float*)d_in[7];
  const float* enc_ffn_W2         = (const float*)d_in[8];
  const float* enc_fourier_W      = (const float*)d_in[9];
  const float* enc_norm_g         = (const float*)d_in[10];
  const float* enc_norm_b         = (const float*)d_in[11];
  const float* dec_qkvo_W         = (const float*)d_in[12];
  const float* dec_qkvo_b         = (const float*)d_in[13];
  const float* dec_ffn_W1         = (const float*)d_in[14];
  const float* dec_ffn_W2         = (const float*)d_in[15];
  const float* dec_self_fourier_W = (const float*)d_in[16];
  const float* dec_cross_fourier_W= (const float*)d_in[17];
  const float* dec_trend_proj_W   = (const float*)d_in[18];
  const float* dec_norm_g         = (const float*)d_in[19];
  const float* dec_norm_b         = (const float*)d_in[20];
  const float* final_W            = (const float*)d_in[21];
  const float* final_b            = (const float*)d_in[22];
  float* out = (float*)d_out;

  float* ws = (float*)d_ws;
  const size_t SZ = (size_t)NB * L * Dm;  // 8,388,608 floats
  float* S_enc = ws;
  float* S_dec = ws + SZ;
  float* S_q   = ws + 2 * SZ;   // FFN hidden uses [S_q, S_i) = 2*SZ = 8192x2048
  float* S_i   = ws + 3 * SZ;
  float* S_z   = ws + 4 * SZ;
  float* S_x1  = ws + 5 * SZ;
  float* T_sum = ws + 6 * SZ;
  float* sm = ws + 7 * SZ;
  float* spec_q  = sm; sm += 262144;
  float* spec_k  = sm; sm += 262144;
  float* spec_o  = sm; sm += 262144;
  float* spec_o2 = sm; sm += 262144;
  float* spec_s  = sm; sm += 524288;
  float* mean_bf = sm; sm += 128;
  float* cm      = sm; sm += 2048;
  float* sinit   = sm; sm += (size_t)NB * L * NF;
  float* tinit   = sm; sm += (size_t)NB * L * NF;
  float* RT      = sm; sm += (size_t)NB * L * NF;

  enum { MODE_BIAS, MODE_BIAS_RES, MODE_GELU, MODE_RES };
  auto gemm = [&](const float* A, const float* W, const float* bias, const float* R,
                  float* C, int Mr, int N, int K, int mode) {
    dim3 grid((unsigned)((Mr >> 7) * (N >> 7)));
    if (mode == MODE_BIAS)
      k_bgemm<true, false, false><<<grid, 256, 0, stream>>>(A, W, bias, nullptr, C, N, K);
    else if (mode == MODE_BIAS_RES)
      k_bgemm<true, true, false><<<grid, 256, 0, stream>>>(A, W, bias, R, C, N, K);
    else if (mode == MODE_GELU)
      k_bgemm<false, false, true><<<grid, 256, 0, stream>>>(A, W, nullptr, nullptr, C, N, K);
    else
      k_bgemm<false, true, false><<<grid, 256, 0, stream>>>(A, W, nullptr, R, C, N, K);
  };
  auto dft = [&](const float* A, float* S) {
    hipMemsetAsync(S, 0, 262144 * sizeof(float), stream);
    k_dft<<<dim3(16, 8, NB), 256, 0, stream>>>(A, S);
  };
  auto decomp = [&](int tmode, const float* Z, float* Sout, float* T) {
    if (tmode == 0)      k_decomp2<0><<<NB * 64, 512, 0, stream>>>(Z, Sout, T);
    else if (tmode == 1) k_decomp2<1><<<NB * 64, 512, 0, stream>>>(Z, Sout, T);
    else                 k_decomp2<2><<<NB * 64, 512, 0, stream>>>(Z, Sout, T);
  };

  const int MR = NB * L;           // 16384 rows
  const int RW = 8192;             // FFN row chunk
  const size_t CH = (size_t)RW * Dm;

  // ---- Phase A: init + embeddings ----
  k_enc_mean<<<NB * NF, 256, 0, stream>>>(x_enc, mean_bf);
  k_init_decomp<<<(NB * L * NF + 255) / 256, 256, 0, stream>>>(x_enc, mean_bf, sinit, tinit);
  k_embed2<<<NB * 512, 256, 0, stream>>>(x_enc, enc_emb_W, S_enc);

  // ---- Phase B: encoder x2 (shared Fourier weights) ----
  for (int layer = 0; layer < 2; ++layer) {
    const float* Wl = enc_qkvo_W + (size_t)layer * 4 * Dm * Dm;
    const float* bl = enc_qkvo_b + (size_t)layer * 4 * Dm;
    gemm(S_enc, Wl, bl, nullptr, S_q, MR, Dm, Dm, MODE_BIAS);            // q proj
    dft(S_q, spec_q);
    k_cmul<<<NB * NH * NM, 64, 0, stream>>>(spec_q, enc_fourier_W, spec_o);
    k_irdft<<<dim3(64, 8, NB), 256, 0, stream>>>(spec_o, S_i, 1.0f / L);
    gemm(S_i, Wl + 3 * Dm * Dm, bl + 3 * Dm, S_enc, S_z, MR, Dm, Dm, MODE_BIAS_RES);
    decomp(0, S_z, S_x1, nullptr);
    for (int ch = 0; ch < 2; ++ch) {
      gemm(S_x1 + ch * CH, enc_ffn_W1 + (size_t)layer * DFF * Dm, nullptr, nullptr,
           S_q, RW, DFF, Dm, MODE_GELU);
      gemm(S_q, enc_ffn_W2 + (size_t)layer * Dm * DFF, nullptr, S_x1 + ch * CH,
           S_z + ch * CH, RW, Dm, DFF, MODE_RES);
    }
    decomp(0, S_z, S_enc, nullptr);
  }
  // my_layernorm(enc_out)
  k_ln<<<NB * L, 256, 0, stream>>>(S_enc, enc_norm_g, enc_norm_b, S_z);
  hipMemsetAsync(cm, 0, 2048 * sizeof(float), stream);
  k_colsum<<<dim3(NB, 2, 32), 256, 0, stream>>>(S_z, cm);
  k_sub<<<32768, 256, 0, stream>>>(S_z, cm, S_enc);

  // ---- Phase C: decoder ----
  k_embed2<<<NB * 512, 256, 0, stream>>>(sinit, dec_emb_W, S_dec);
  // self attention
  {
    const float* Wl = dec_qkvo_W;
    const float* bl = dec_qkvo_b;
    gemm(S_dec, Wl, bl, nullptr, S_q, MR, Dm, Dm, MODE_BIAS);
    dft(S_q, spec_q);
    k_cmul<<<NB * NH * NM, 64, 0, stream>>>(spec_q, dec_self_fourier_W, spec_o);
    k_irdft<<<dim3(64, 8, NB), 256, 0, stream>>>(spec_o, S_i, 1.0f / L);
    gemm(S_i, Wl + 3 * Dm * Dm, bl + 3 * Dm, S_dec, S_z, MR, Dm, Dm, MODE_BIAS_RES);
    decomp(1, S_z, S_x1, T_sum);
  }
  // cross attention
  {
    const float* Wl = dec_qkvo_W + (size_t)4 * Dm * Dm;
    const float* bl = dec_qkvo_b + 4 * Dm;
    gemm(S_x1, Wl, bl, nullptr, S_q, MR, Dm, Dm, MODE_BIAS);                       // q
    gemm(S_enc, Wl + Dm * Dm, bl + Dm, nullptr, S_i, MR, Dm, Dm, MODE_BIAS);       // k
    dft(S_q, spec_q);
    dft(S_i, spec_k);
    k_cross_s<<<NB * NH, 256, 0, stream>>>(spec_q, spec_k, spec_s);
    k_cross_o<<<NB * NH, 256, 0, stream>>>(spec_s, spec_k, spec_o2);
    k_cmul<<<NB * NH * NM, 64, 0, stream>>>(spec_o2, dec_cross_fourier_W, spec_o);
    k_irdft<<<dim3(64, 8, NB), 256, 0, stream>>>(spec_o, S_i,
                                                 (1.0f / L) / (512.0f * 512.0f));
    gemm(S_i, Wl + 3 * Dm * Dm, bl + 3 * Dm, S_x1, S_z, MR, Dm, Dm, MODE_BIAS_RES);
    decomp(2, S_z, S_dec, T_sum);
  }
  // ffn
  for (int ch = 0; ch < 2; ++ch) {
    gemm(S_dec + ch * CH, dec_ffn_W1, nullptr, nullptr, S_q, RW, DFF, Dm, MODE_GELU);
    gemm(S_q, dec_ffn_W2, nullptr, S_dec + ch * CH, S_z + ch * CH, RW, Dm, DFF, MODE_RES);
  }
  decomp(2, S_z, S_x1, T_sum);
  // trend projection + final
  k_trendproj<<<NB * L, 256, 0, stream>>>(T_sum, dec_trend_proj_W, RT);
  k_ln<<<NB * L, 256, 0, stream>>>(S_x1, dec_norm_g, dec_norm_b, S_z);
  hipMemsetAsync(cm, 0, 2048 * sizeof(float), stream);
  k_colsum<<<dim3(NB, 2, 32), 256, 0, stream>>>(S_z, cm);
  k_final<<<NB * PRED, 256, 0, stream>>>(S_z, cm, final_W, final_b, tinit, RT, out);
}

// Round 4
// 2838.568 us; speedup vs baseline: 2.2717x; 1.0442x over previous
//
#include <hip/hip_runtime.h>
#include <hip/hip_bf16.h>
#include <math.h>

namespace {

constexpr int NB    = 4;
constexpr int L     = 4096;   // SEQ == LDEC
constexpr int PRED  = 2048;
constexpr int LABEL = 2048;
constexpr int NF    = 21;
constexpr int Dm    = 512;
constexpr int NH    = 8;
constexpr int NE    = 64;
constexpr int NM    = 64;
constexpr int DFF   = 2048;
constexpr float TWOPI = 6.283185307179586f;

typedef __attribute__((ext_vector_type(8))) short s16x8;
typedef __attribute__((ext_vector_type(4))) short s16x4;
typedef __attribute__((ext_vector_type(4))) float f32x4;

__device__ inline short f2b(float f) {
  __hip_bfloat16 h = __float2bfloat16(f);
  return __builtin_bit_cast(short, h);
}
__device__ inline float b2f(short s) {
  unsigned u = ((unsigned)(unsigned short)s) << 16;
  return __builtin_bit_cast(float, u);
}

// ---------------- init: column mean of x_enc over time ----------------
__global__ void k_enc_mean(const float* __restrict__ x, float* __restrict__ mean_bf) {
  int bf = blockIdx.x; int b = bf / NF, f = bf % NF;
  const float* p = x + (size_t)b * L * NF + f;
  float s = 0.f;
  for (int l = threadIdx.x; l < L; l += 256) s += p[(size_t)l * NF];
  __shared__ float red[256];
  red[threadIdx.x] = s; __syncthreads();
  for (int st = 128; st > 0; st >>= 1) {
    if (threadIdx.x < st) red[threadIdx.x] += red[threadIdx.x + st];
    __syncthreads();
  }
  if (threadIdx.x == 0) mean_bf[bf] = red[0] * (1.0f / L);
}

// ---------------- init decomp: seasonal_init / trend_init ----------------
__global__ void k_init_decomp(const float* __restrict__ x, const float* __restrict__ mean_bf,
                              float* __restrict__ sinit, float* __restrict__ tinit) {
  int idx = blockIdx.x * 256 + threadIdx.x;
  if (idx >= NB * L * NF) return;
  int f = idx % NF; int t = (idx / NF) % L; int b = idx / (NF * L);
  float sv, tv;
  if (t < LABEL) {
    int l = LABEL + t;
    float s = 0.f;
    #pragma unroll
    for (int j = -12; j <= 12; ++j) {
      int ll = l + j; ll = ll < 0 ? 0 : (ll > L - 1 ? L - 1 : ll);
      s += x[((size_t)b * L + ll) * NF + f];
    }
    float ma = s * (1.0f / 25.0f);
    sv = x[((size_t)b * L + l) * NF + f] - ma;
    tv = ma;
  } else { sv = 0.f; tv = mean_bf[b * NF + f]; }
  sinit[idx] = sv; tinit[idx] = tv;
}

// ---------------- embedding: circular conv3 (NF->Dm) + positional, tiled ----------------
__global__ __launch_bounds__(256) void k_embed2(const float* __restrict__ x,
                                                const float* __restrict__ W,
                                                float* __restrict__ out) {
  int bid = blockIdx.x;
  int dt = bid & 7;
  int lt = (bid >> 3) & 63;
  int b  = bid >> 9;
  int l0 = lt << 6, d0 = dt << 6;
  __shared__ float xs[66][22];
  __shared__ float wt[63][68];
  int t = threadIdx.x;
  for (int i = t; i < 66 * 21; i += 256) {
    int r = i / 21, f = i - r * 21;
    int l = (l0 - 1 + r) & (L - 1);
    xs[r][f] = x[((size_t)b * L + l) * NF + f];
  }
  for (int i = t; i < 63 * 64; i += 256) {
    int k = i >> 6, dd = i & 63;
    wt[k][dd] = W[(size_t)(d0 + dd) * 63 + k];
  }
  __syncthreads();
  int tx = t & 15, ty = t >> 4;
  float acc[4][4] = {};
  #pragma unroll
  for (int f = 0; f < 21; ++f) {
    #pragma unroll
    for (int j = 0; j < 3; ++j) {
      int k = f * 3 + j;
      float xv[4], wv[4];
      #pragma unroll
      for (int i = 0; i < 4; ++i) xv[i] = xs[ty * 4 + i + j][f];
      #pragma unroll
      for (int jj = 0; jj < 4; ++jj) wv[jj] = wt[k][tx * 4 + jj];
      #pragma unroll
      for (int i = 0; i < 4; ++i)
        #pragma unroll
        for (int jj = 0; jj < 4; ++jj) acc[i][jj] += xv[i] * wv[jj];
    }
  }
  #pragma unroll
  for (int i = 0; i < 4; ++i) {
    int l = l0 + ty * 4 + i;
    #pragma unroll
    for (int jj = 0; jj < 4; ++jj) {
      int d = d0 + tx * 4 + jj;
      float dv = expf((float)(d & ~1) * (-9.210340371976184f / 512.0f));
      float ang = (float)l * dv;
      float pe = (d & 1) ? cosf(ang) : sinf(ang);
      out[((size_t)b * L + l) * Dm + d] = acc[i][jj] + pe;
    }
  }
}

// ---------------- bf16 MFMA GEMM: C = A @ W^T (+bias)(+gelu)(+res), fp32 in/out ----------------
template<bool BIAS, bool RES, bool GELU>
__global__ __launch_bounds__(256) void k_bgemm(const float* __restrict__ A, const float* __restrict__ W,
                       const float* __restrict__ bias, const float* __restrict__ R,
                       float* __restrict__ C, int N, int K) {
  __shared__ __align__(16) short As[128 * 64];
  __shared__ __align__(16) short Bs[128 * 64];
  int nt = N >> 7;
  int n0 = (blockIdx.x % nt) << 7;
  int m0 = (int)(blockIdx.x / nt) << 7;
  int t = threadIdx.x;
  int row = t >> 1;
  int kh = (t & 1) << 5;
  const float* Ap = A + (size_t)(m0 + row) * K + kh;
  const float* Wp = W + (size_t)(n0 + row) * K + kh;
  int wbase = row * 128 + (t & 1) * 64;
  int swz = (row & 7) << 4;
  int lane = t & 63, w = t >> 6;
  int wr = (w >> 1) << 6, wc = (w & 1) << 6;
  int fr_a = wr + (lane & 15);
  int fr_b = wc + (lane & 15);
  int kg = (lane >> 4) << 4;
  f32x4 ra[8], rb[8];
  f32x4 acc[4][4] = {};

  #pragma unroll
  for (int q = 0; q < 8; ++q) {
    ra[q] = *(const f32x4*)(Ap + q * 4);
    rb[q] = *(const f32x4*)(Wp + q * 4);
  }
  for (int k0 = 0; k0 < K; k0 += 64) {
    if (k0) __syncthreads();
    #pragma unroll
    for (int h = 0; h < 4; ++h) {
      s16x8 va, vb;
      #pragma unroll
      for (int e = 0; e < 8; ++e) {
        va[e] = f2b(ra[h * 2 + (e >> 2)][e & 3]);
        vb[e] = f2b(rb[h * 2 + (e >> 2)][e & 3]);
      }
      int wb = (wbase + h * 16) ^ swz;
      *(s16x8*)((char*)As + wb) = va;
      *(s16x8*)((char*)Bs + wb) = vb;
    }
    __syncthreads();
    if (k0 + 64 < K) {
      #pragma unroll
      for (int q = 0; q < 8; ++q) {
        ra[q] = *(const f32x4*)(Ap + k0 + 64 + q * 4);
        rb[q] = *(const f32x4*)(Wp + k0 + 64 + q * 4);
      }
    }
    #pragma unroll
    for (int ks = 0; ks < 2; ++ks) {
      s16x8 af[4], bfr[4];
      #pragma unroll
      for (int f = 0; f < 4; ++f) {
        int r1 = fr_a + f * 16;
        af[f] = *(const s16x8*)((const char*)As + ((r1 * 128 + ks * 64 + kg) ^ ((r1 & 7) << 4)));
        int r2 = fr_b + f * 16;
        bfr[f] = *(const s16x8*)((const char*)Bs + ((r2 * 128 + ks * 64 + kg) ^ ((r2 & 7) << 4)));
      }
      #pragma unroll
      for (int fm = 0; fm < 4; ++fm)
        #pragma unroll
        for (int fn = 0; fn < 4; ++fn)
          acc[fm][fn] = __builtin_amdgcn_mfma_f32_16x16x32_bf16(af[fm], bfr[fn], acc[fm][fn], 0, 0, 0);
    }
  }
  int em = m0 + wr + (lane >> 4) * 4;
  int en = n0 + wc + (lane & 15);
  #pragma unroll
  for (int fm = 0; fm < 4; ++fm) {
    #pragma unroll
    for (int fn = 0; fn < 4; ++fn) {
      int n = en + fn * 16;
      #pragma unroll
      for (int r = 0; r < 4; ++r) {
        int m = em + fm * 16 + r;
        float v = acc[fm][fn][r];
        if (BIAS) v += bias[n];
        if (GELU) v = 0.5f * v * (1.0f + erff(v * 0.70710678118654752f));
        if (RES)  v += R[(size_t)m * N + n];
        C[(size_t)m * N + n] = v;
      }
    }
  }
}

// ---------------- twiddle tables (bf16), regenerated every launch ----------------
// Fm[m2][l]: m2<64 -> cos(2pi m l/L), else -sin.  Gt[l][m2]: irfft coeffs.
__global__ void k_gentw(short* __restrict__ fm, short* __restrict__ gt) {
  int idx = blockIdx.x * 256 + threadIdx.x;
  {
    int m2 = idx >> 12, l = idx & 4095;
    int m = m2 & 63;
    int ph = (m * l) & (L - 1);
    float sv, cv;
    __sincosf((float)ph * (TWOPI / L), &sv, &cv);
    fm[idx] = f2b((m2 < 64) ? cv : -sv);
  }
  {
    int l = idx >> 7, m2 = idx & 127;
    int m = m2 & 63;
    int ph = (m * l) & (L - 1);
    float sv, cv;
    __sincosf((float)ph * (TWOPI / L), &sv, &cv);
    float g;
    if (m2 == 0) g = 1.0f;
    else if (m2 == 64) g = 0.0f;
    else g = (m2 < 64) ? 2.0f * cv : -2.0f * sv;
    gt[idx] = f2b(g);
  }
}

// ---------------- MFMA forward DFT: S[b][c][m2] += sum_l A[b][l][c] * Fm[m2][l] ----------------
// grid 256: kseg(16) x ctile(4) x b(4). Tile 128c x 128m, K=256 per block, split-K atomics.
__global__ __launch_bounds__(256) void k_dft_mfma(const float* __restrict__ A,
                                                  const short* __restrict__ Fm,
                                                  float* __restrict__ S) {
  __shared__ __align__(16) short As[128 * 128];  // [c][l], XOR ((c&15)<<4)
  __shared__ __align__(16) short Bs[128 * 128];  // [m][l], XOR ((m&15)<<4)
  int bid = blockIdx.x;
  int kseg = bid & 15, ct = (bid >> 4) & 3, b = bid >> 6;
  int c0 = ct << 7;
  int lbase = kseg << 8;
  int t = threadIdx.x;
  int lane = t & 63, w = t >> 6;
  int wr = (w >> 1) << 6, wc = (w & 1) << 6;
  f32x4 acc[4][4] = {};
  const float* Ab = A + (size_t)b * L * Dm;

  for (int k0 = 0; k0 < 256; k0 += 128) {
    if (k0) __syncthreads();
    // stage A (transpose fp32 (l,c) -> bf16 LDS [c][l])
    #pragma unroll
    for (int it = 0; it < 4; ++it) {
      int s = it * 256 + t;
      int cq = (s & 31) << 2;
      int lq = (s >> 5) << 2;
      f32x4 r0 = *(const f32x4*)(Ab + (size_t)(lbase + k0 + lq + 0) * Dm + c0 + cq);
      f32x4 r1 = *(const f32x4*)(Ab + (size_t)(lbase + k0 + lq + 1) * Dm + c0 + cq);
      f32x4 r2 = *(const f32x4*)(Ab + (size_t)(lbase + k0 + lq + 2) * Dm + c0 + cq);
      f32x4 r3 = *(const f32x4*)(Ab + (size_t)(lbase + k0 + lq + 3) * Dm + c0 + cq);
      #pragma unroll
      for (int j = 0; j < 4; ++j) {
        int crow = cq + j;
        s16x4 p;
        p[0] = f2b(r0[j]); p[1] = f2b(r1[j]); p[2] = f2b(r2[j]); p[3] = f2b(r3[j]);
        *(s16x4*)((char*)As + crow * 256 + ((lq * 2) ^ ((crow & 15) << 4))) = p;
      }
    }
    // stage B (Fm rows, linear copy with XOR)
    #pragma unroll
    for (int it = 0; it < 8; ++it) {
      int m = it * 16 + (t >> 4);
      int lb = (t & 15) * 8;
      s16x8 v = *(const s16x8*)(Fm + (size_t)m * L + lbase + k0 + lb);
      *(s16x8*)((char*)Bs + m * 256 + ((lb * 2) ^ ((m & 15) << 4))) = v;
    }
    __syncthreads();
    #pragma unroll
    for (int ks = 0; ks < 4; ++ks) {
      int kb = ks * 64 + ((lane >> 4) << 4);
      s16x8 af[4], bf_[4];
      #pragma unroll
      for (int f = 0; f < 4; ++f) {
        int fr = wr + (lane & 15) + f * 16;
        af[f] = *(const s16x8*)((const char*)As + fr * 256 + (kb ^ ((fr & 15) << 4)));
        int mr = wc + (lane & 15) + f * 16;
        bf_[f] = *(const s16x8*)((const char*)Bs + mr * 256 + (kb ^ ((mr & 15) << 4)));
      }
      #pragma unroll
      for (int fm = 0; fm < 4; ++fm)
        #pragma unroll
        for (int fn = 0; fn < 4; ++fn)
          acc[fm][fn] = __builtin_amdgcn_mfma_f32_16x16x32_bf16(af[fm], bf_[fn], acc[fm][fn], 0, 0, 0);
    }
  }
  float* Sb = S + (size_t)b * Dm * 128;
  int ec = c0 + wr + ((lane >> 4) << 2);
  int em = wc + (lane & 15);
  #pragma unroll
  for (int fm = 0; fm < 4; ++fm)
    #pragma unroll
    for (int fn = 0; fn < 4; ++fn)
      #pragma unroll
      for (int r = 0; r < 4; ++r)
        atomicAdd(&Sb[(size_t)(ec + fm * 16 + r) * 128 + em + fn * 16], acc[fm][fn][r]);
}

// ---------------- MFMA inverse DFT: O[b][c][l] = scale * sum_m S[b][c][m] * Gt[l][m] ----------------
// grid 512: ltile(32) x ctile(4) x b(4). K = 128 (single pass), direct store.
__global__ __launch_bounds__(256) void k_irdft_mfma(const float* __restrict__ S,
                                                    const short* __restrict__ Gt,
                                                    float* __restrict__ O, float scale) {
  __shared__ __align__(16) short As[128 * 128];  // [c][m], XOR ((c&15)<<4)
  __shared__ __align__(16) short Bs[128 * 128];  // [l][m], XOR ((l&15)<<4)
  int bid = blockIdx.x;
  int lt = bid & 31, ct = (bid >> 5) & 3, b = bid >> 7;
  int c0 = ct << 7;
  int l0t = lt << 7;
  int t = threadIdx.x;
  int lane = t & 63, w = t >> 6;
  int wr = (w >> 1) << 6, wc = (w & 1) << 6;
  f32x4 acc[4][4] = {};
  // stage A: spec fp32 -> bf16
  #pragma unroll
  for (int it = 0; it < 8; ++it) {
    int c = it * 16 + (t >> 4);
    int me = (t & 15) * 8;
    const float* sp = S + ((size_t)b * Dm + c0 + c) * 128 + me;
    f32x4 v0 = *(const f32x4*)sp;
    f32x4 v1 = *(const f32x4*)(sp + 4);
    s16x8 p;
    p[0]=f2b(v0[0]); p[1]=f2b(v0[1]); p[2]=f2b(v0[2]); p[3]=f2b(v0[3]);
    p[4]=f2b(v1[0]); p[5]=f2b(v1[1]); p[6]=f2b(v1[2]); p[7]=f2b(v1[3]);
    *(s16x8*)((char*)As + c * 256 + ((me * 2) ^ ((c & 15) << 4))) = p;
  }
  // stage B: Gt rows
  #pragma unroll
  for (int it = 0; it < 8; ++it) {
    int l = it * 16 + (t >> 4);
    int me = (t & 15) * 8;
    s16x8 v = *(const s16x8*)(Gt + (size_t)(l0t + l) * 128 + me);
    *(s16x8*)((char*)Bs + l * 256 + ((me * 2) ^ ((l & 15) << 4))) = v;
  }
  __syncthreads();
  #pragma unroll
  for (int ks = 0; ks < 4; ++ks) {
    int kb = ks * 64 + ((lane >> 4) << 4);
    s16x8 af[4], bf_[4];
    #pragma unroll
    for (int f = 0; f < 4; ++f) {
      int fr = wr + (lane & 15) + f * 16;
      af[f] = *(const s16x8*)((const char*)As + fr * 256 + (kb ^ ((fr & 15) << 4)));
      int lr = wc + (lane & 15) + f * 16;
      bf_[f] = *(const s16x8*)((const char*)Bs + lr * 256 + (kb ^ ((lr & 15) << 4)));
    }
    #pragma unroll
    for (int fm = 0; fm < 4; ++fm)
      #pragma unroll
      for (int fn = 0; fn < 4; ++fn)
        acc[fm][fn] = __builtin_amdgcn_mfma_f32_16x16x32_bf16(af[fm], bf_[fn], acc[fm][fn], 0, 0, 0);
  }
  float* Ob = O + (size_t)b * Dm * L;
  int ec = c0 + wr + ((lane >> 4) << 2);
  int el = l0t + wc + (lane & 15);
  #pragma unroll
  for (int fm = 0; fm < 4; ++fm)
    #pragma unroll
    for (int fn = 0; fn < 4; ++fn)
      #pragma unroll
      for (int r = 0; r < 4; ++r)
        Ob[(size_t)(ec + fm * 16 + r) * L + el + fn * 16] = scale * acc[fm][fn][r];
}

// ---------------- per-mode complex channel mix (coalesced W reads) ----------------
// grid 128: (b*8+h)*4+og. threads: o_loc = t>>4 (16 o), msub = t&15 (4 m each).
__global__ __launch_bounds__(256) void k_cmul2(const float* __restrict__ S, const float* __restrict__ Wf,
                                               float* __restrict__ O) {
  __shared__ float q[64 * 128];
  int bid = blockIdx.x;
  int og = bid & 3, h = (bid >> 2) & 7, b = bid >> 5;
  int t = threadIdx.x;
  const float* Sb = S + ((size_t)b * Dm + h * NE) * 128;
  for (int i = t; i < 8192; i += 256) q[i] = Sb[i];
  __syncthreads();
  int o = og * 16 + (t >> 4);
  int m0 = (t & 15) * 4;
  float ar[4] = {}, ai[4] = {};
  for (int i = 0; i < 64; ++i) {
    const float* wrow = Wf + (((size_t)h * 64 + i) * 64 + o) * 128 + m0 * 2;
    float wv[8];
    *(f32x4*)wv = *(const f32x4*)wrow;
    *(f32x4*)(wv + 4) = *(const f32x4*)(wrow + 4);
    const float* qi_ = q + i * 128;
    #pragma unroll
    for (int k = 0; k < 4; ++k) {
      float qr = qi_[m0 + k], qim = qi_[64 + m0 + k];
      float wr = wv[2 * k], wi = wv[2 * k + 1];
      ar[k] += qr * wr - qim * wi;
      ai[k] += qr * wi + qim * wr;
    }
  }
  float* Ob = O + ((size_t)b * Dm + h * NE + o) * 128;
  f32x4 vr, vi;
  #pragma unroll
  for (int k = 0; k < 4; ++k) { vr[k] = ar[k]; vi[k] = ai[k]; }
  *(f32x4*)(Ob + m0) = vr;
  *(f32x4*)(Ob + 64 + m0) = vi;
}

// ---------------- cross: s[x,y] = ctanh(sum_e qf[e,x]*kf[e,y]) ----------------
__global__ void k_cross_s(const float* __restrict__ Sq, const float* __restrict__ Sk,
                          float* __restrict__ Sout) {
  int bh = blockIdx.x;
  int b = bh >> 3, h = bh & 7;
  __shared__ float Qr[64][64], Qi[64][64], Kr[64][64], Ki[64][64];
  int t = threadIdx.x;
  const float* qb = Sq + ((size_t)b * Dm + h * NE) * 128;
  const float* kb = Sk + ((size_t)b * Dm + h * NE) * 128;
  for (int idx = t; idx < 4096; idx += 256) {
    int e = idx >> 6, x = idx & 63;
    Qr[e][x] = qb[e * 128 + x];
    Qi[e][x] = qb[e * 128 + 64 + x];
    Kr[e][x] = kb[e * 128 + x];
    Ki[e][x] = kb[e * 128 + 64 + x];
  }
  __syncthreads();
  int tx = t & 15, ty = t >> 4;
  float ar[4][4] = {}, ai[4][4] = {};
  for (int e = 0; e < 64; ++e) {
    float qr[4], qi[4], kr[4], ki[4];
    #pragma unroll
    for (int i = 0; i < 4; ++i) { qr[i] = Qr[e][(ty << 2) + i]; qi[i] = Qi[e][(ty << 2) + i]; }
    #pragma unroll
    for (int j = 0; j < 4; ++j) { kr[j] = Kr[e][(tx << 2) + j]; ki[j] = Ki[e][(tx << 2) + j]; }
    #pragma unroll
    for (int i = 0; i < 4; ++i)
      #pragma unroll
      for (int j = 0; j < 4; ++j) {
        ar[i][j] += qr[i] * kr[j] - qi[i] * ki[j];
        ai[i][j] += qr[i] * ki[j] + qi[i] * kr[j];
      }
  }
  float* sp = Sout + (size_t)bh * 4096 * 2;
  #pragma unroll
  for (int i = 0; i < 4; ++i)
    #pragma unroll
    for (int j = 0; j < 4; ++j) {
      int x = (ty << 2) + i, y = (tx << 2) + j;
      float a = ar[i][j], bb = ai[i][j];
      float th = tanhf(a);
      float u = tanf(bb);
      float re, im;
      if (fabsf(u) <= 1.0f) {
        float dn = 1.0f + th * th * u * u;
        re = th * (1.0f + u * u) / dn;
        im = u * (1.0f - th * th) / dn;
      } else {
        float iu = 1.0f / u;
        float dn = iu * iu + th * th;
        re = th * (iu * iu + 1.0f) / dn;
        im = iu * (1.0f - th * th) / dn;
      }
      sp[(x * 64 + y) * 2]     = re;
      sp[(x * 64 + y) * 2 + 1] = im;
    }
}

// ---------------- cross: o[e,x] = sum_y s[x,y]*kf[e,y] ----------------
__global__ void k_cross_o(const float* __restrict__ Sin, const float* __restrict__ Sk,
                          float* __restrict__ O2) {
  int bh = blockIdx.x;
  int b = bh >> 3, h = bh & 7;
  __shared__ float SrT[64][64], SiT[64][64], KrT[64][64], KiT[64][64];
  int t = threadIdx.x;
  const float* sp = Sin + (size_t)bh * 8192;
  const float* kb = Sk + ((size_t)b * Dm + h * NE) * 128;
  for (int idx = t; idx < 4096; idx += 256) {
    int r = idx >> 6, c = idx & 63;
    SrT[c][r] = sp[idx * 2];
    SiT[c][r] = sp[idx * 2 + 1];
    KrT[c][r] = kb[r * 128 + c];
    KiT[c][r] = kb[r * 128 + 64 + c];
  }
  __syncthreads();
  int tx = t & 15, ty = t >> 4;
  float ar[4][4] = {}, ai[4][4] = {};
  for (int y = 0; y < 64; ++y) {
    float kr[4], ki[4], sr[4], si[4];
    #pragma unroll
    for (int i = 0; i < 4; ++i) { kr[i] = KrT[y][(ty << 2) + i]; ki[i] = KiT[y][(ty << 2) + i]; }
    #pragma unroll
    for (int j = 0; j < 4; ++j) { sr[j] = SrT[y][(tx << 2) + j]; si[j] = SiT[y][(tx << 2) + j]; }
    #pragma unroll
    for (int i = 0; i < 4; ++i)
      #pragma unroll
      for (int j = 0; j < 4; ++j) {
        ar[i][j] += sr[j] * kr[i] - si[j] * ki[i];
        ai[i][j] += sr[j] * ki[i] + si[j] * kr[i];
      }
  }
  float* ob = O2 + ((size_t)b * Dm + h * NE) * 128;
  #pragma unroll
  for (int i = 0; i < 4; ++i)
    #pragma unroll
    for (int j = 0; j < 4; ++j) {
      int e = (ty << 2) + i, x = (tx << 2) + j;
      ob[e * 128 + x]      = ar[i][j];
      ob[e * 128 + 64 + x] = ai[i][j];
    }
}

// ---------------- series_decomp (sliding window): seasonal = z - MA25(z) ----------------
template<int TMODE> // 0 none, 1 write trend, 2 add trend
__global__ __launch_bounds__(512) void k_decomp2(const float* __restrict__ Z, float* __restrict__ Sout,
                          float* __restrict__ T) {
  int b = blockIdx.x >> 7;
  int l0 = (blockIdx.x & 127) << 5;
  int d = threadIdx.x;
  const float* zb = Z + (size_t)b * L * Dm + d;
  float s = 0.f;
  #pragma unroll
  for (int j = -12; j <= 12; ++j) {
    int ll = l0 + j; ll = ll < 0 ? 0 : ll;
    s += zb[(size_t)ll * Dm];
  }
  for (int i = 0; i < 32; ++i) {
    int l = l0 + i;
    float ma = s * (1.0f / 25.0f);
    size_t idx = ((size_t)b * L + l) * Dm + d;
    Sout[idx] = zb[(size_t)l * Dm] - ma;
    if (TMODE == 1) T[idx] = ma;
    else if (TMODE == 2) T[idx] += ma;
    int la = l + 13; la = la > L - 1 ? L - 1 : la;
    int lr = l - 12; lr = lr < 0 ? 0 : lr;
    s += zb[(size_t)la * Dm] - zb[(size_t)lr * Dm];
  }
}

// ---------------- row LayerNorm over Dm ----------------
__global__ void k_ln(const float* __restrict__ X, const float* __restrict__ g,
                     const float* __restrict__ be, float* __restrict__ Y) {
  int row = blockIdx.x;
  const float* x = X + (size_t)row * Dm;
  int t = threadIdx.x;
  float v0 = x[t], v1 = x[t + 256];
  float s = v0 + v1;
  __shared__ float red[4];
  #pragma unroll
  for (int off = 32; off > 0; off >>= 1) s += __shfl_down(s, off);
  int wid = t >> 6, lane = t & 63;
  if (lane == 0) red[wid] = s;
  __syncthreads();
  float mu = (red[0] + red[1] + red[2] + red[3]) * (1.0f / Dm);
  float e0 = v0 - mu, e1 = v1 - mu;
  float s2 = e0 * e0 + e1 * e1;
  #pragma unroll
  for (int off = 32; off > 0; off >>= 1) s2 += __shfl_down(s2, off);
  __syncthreads();
  if (lane == 0) red[wid] = s2;
  __syncthreads();
  float var = (red[0] + red[1] + red[2] + red[3]) * (1.0f / Dm);
  float rstd = rsqrtf(var + 1e-5f);
  float* y = Y + (size_t)row * Dm;
  y[t]       = e0 * rstd * g[t] + be[t];
  y[t + 256] = e1 * rstd * g[t + 256] + be[t + 256];
}

// ---------------- column sums over time (for my_layernorm mean) ----------------
__global__ void k_colsum(const float* __restrict__ X, float* __restrict__ cm) {
  int b = blockIdx.x;
  int d = blockIdx.y * 256 + threadIdx.x;
  int lc = blockIdx.z;
  const float* x = X + ((size_t)b * L + (size_t)lc * 128) * Dm + d;
  float s = 0.f;
  for (int i = 0; i < 128; ++i) s += x[(size_t)i * Dm];
  atomicAdd(&cm[b * Dm + d], s);
}

__global__ void k_sub(const float* __restrict__ X, const float* __restrict__ cm,
                      float* __restrict__ Y) {
  size_t idx = (size_t)blockIdx.x * 256 + threadIdx.x;
  int d = (int)(idx & (Dm - 1));
  int b = (int)(idx >> 21);
  Y[idx] = X[idx] - cm[b * Dm + d] * (1.0f / L);
}

// ---------------- trend projection: circular conv3 (Dm -> NF), W in LDS bf16 ----------------
__global__ __launch_bounds__(256) void k_trendproj2(const float* __restrict__ T,
                                                    const float* __restrict__ Wp,
                                                    float* __restrict__ RT) {
  __shared__ short wlds[NF * 512 * 3];  // 64512 B
  int t = threadIdx.x;
  for (int i = t; i < NF * 512 * 3; i += 256) wlds[i] = f2b(Wp[i]);
  __syncthreads();
  int b = blockIdx.x >> 6;
  int l0 = (blockIdx.x & 63) << 6;
  int w = t >> 6, lane = t & 63;
  const float* Tb = T + (size_t)b * L * Dm;
  for (int r = w; r < 64; r += 4) {
    int l = l0 + r;
    int lm = (l - 1) & (L - 1), lp = (l + 1) & (L - 1);
    float acc[NF];
    #pragma unroll
    for (int f = 0; f < NF; ++f) acc[f] = 0.f;
    #pragma unroll 2
    for (int dblk = 0; dblk < 8; ++dblk) {
      int d = dblk * 64 + lane;
      float t0 = Tb[(size_t)lm * Dm + d];
      float t1 = Tb[(size_t)l  * Dm + d];
      float t2 = Tb[(size_t)lp * Dm + d];
      #pragma unroll
      for (int f = 0; f < NF; ++f) {
        const short* wp = &wlds[(f * 512 + d) * 3];
        acc[f] += t0 * b2f(wp[0]) + t1 * b2f(wp[1]) + t2 * b2f(wp[2]);
      }
    }
    #pragma unroll
    for (int f = 0; f < NF; ++f) {
      float s = acc[f];
      #pragma unroll
      for (int off = 32; off > 0; off >>= 1) s += __shfl_down(s, off);
      if (lane == 0) RT[((size_t)b * L + l) * NF + f] = s;
    }
  }
}

// ---------------- final: out = tinit + RT + my_ln(x) @ Wf^T + bf ----------------
__global__ void k_final(const float* __restrict__ X, const float* __restrict__ cm,
                        const float* __restrict__ Wf, const float* __restrict__ bf,
                        const float* __restrict__ tinit, const float* __restrict__ RT,
                        float* __restrict__ out) {
  int bt = blockIdx.x; int b = bt / PRED, tt = bt % PRED;
  int l = LABEL + tt;
  __shared__ float row[512];
  __shared__ float partial[NF][9];
  int t = threadIdx.x;
  const float* x = X + ((size_t)b * L + l) * Dm;
  const float* c = cm + b * Dm;
  row[t]       = x[t]       - c[t]       * (1.0f / L);
  row[t + 256] = x[t + 256] - c[t + 256] * (1.0f / L);
  __syncthreads();
  if (t < 168) {
    int f = t >> 3, p = t & 7;
    const float* w = Wf + (size_t)f * Dm + p * 64;
    float s = 0.f;
    #pragma unroll
    for (int q = 0; q < 64; ++q) s += row[p * 64 + q] * w[q];
    partial[f][p] = s;
  }
  __syncthreads();
  if (t < NF) {
    float s = bf[t];
    #pragma unroll
    for (int p = 0; p < 8; ++p) s += partial[t][p];
    size_t src = ((size_t)b * L + l) * NF + t;
    out[((size_t)b * PRED + tt) * NF + t] = s + tinit[src] + RT[src];
  }
}

} // namespace

extern "C" void kernel_launch(void* const* d_in, const int* in_sizes, int n_in,
                              void* d_out, int out_size, void* d_ws, size_t ws_size,
                              hipStream_t stream) {
  (void)in_sizes; (void)n_in; (void)out_size; (void)ws_size;
  const float* x_enc              = (const float*)d_in[0];
  const float* enc_emb_W          = (const float*)d_in[3];
  const float* dec_emb_W          = (const float*)d_in[4];
  const float* enc_qkvo_W         = (const float*)d_in[5];
  const float* enc_qkvo_b         = (const float*)d_in[6];
  const float* enc_ffn_W1         = (const float*)d_in[7];
  const float* enc_ffn_W2         = (const float*)d_in[8];
  const float* enc_fourier_W      = (const float*)d_in[9];
  const float* enc_norm_g         = (const float*)d_in[10];
  const float* enc_norm_b         = (const float*)d_in[11];
  const float* dec_qkvo_W         = (const float*)d_in[12];
  const float* dec_qkvo_b         = (const float*)d_in[13];
  const float* dec_ffn_W1         = (const float*)d_in[14];
  const float* dec_ffn_W2         = (const float*)d_in[15];
  const float* dec_self_fourier_W = (const float*)d_in[16];
  const float* dec_cross_fourier_W= (const float*)d_in[17];
  const float* dec_trend_proj_W   = (const float*)d_in[18];
  const float* dec_norm_g         = (const float*)d_in[19];
  const float* dec_norm_b         = (const float*)d_in[20];
  const float* final_W            = (const float*)d_in[21];
  const float* final_b            = (const float*)d_in[22];
  float* out = (float*)d_out;

  float* ws = (float*)d_ws;
  const size_t SZ = (size_t)NB * L * Dm;  // 8,388,608 floats
  float* S_enc = ws;
  float* S_dec = ws + SZ;
  float* S_q   = ws + 2 * SZ;   // FFN hidden uses [S_q, S_i) = 8192x2048
  float* S_i   = ws + 3 * SZ;
  float* S_z   = ws + 4 * SZ;
  float* S_x1  = ws + 5 * SZ;
  float* T_sum = ws + 6 * SZ;
  float* sm = ws + 7 * SZ;
  float* spec_q  = sm; sm += 262144;
  float* spec_k  = sm; sm += 262144;
  float* spec_o  = sm; sm += 262144;
  float* spec_o2 = sm; sm += 262144;
  float* spec_s  = sm; sm += 524288;
  float* mean_bf = sm; sm += 128;
  float* cm      = sm; sm += 2048;
  float* sinit   = sm; sm += (size_t)NB * L * NF;
  float* tinit   = sm; sm += (size_t)NB * L * NF;
  float* RT      = sm; sm += (size_t)NB * L * NF;
  short* fm_tw   = (short*)sm; sm += 262144;   // 128*4096 bf16
  short* gt_tw   = (short*)sm; sm += 262144;   // 4096*128 bf16

  enum { MODE_BIAS, MODE_BIAS_RES, MODE_GELU, MODE_RES };
  auto gemm = [&](const float* A, const float* W, const float* bias, const float* R,
                  float* C, int Mr, int N, int K, int mode) {
    dim3 grid((unsigned)((Mr >> 7) * (N >> 7)));
    if (mode == MODE_BIAS)
      k_bgemm<true, false, false><<<grid, 256, 0, stream>>>(A, W, bias, nullptr, C, N, K);
    else if (mode == MODE_BIAS_RES)
      k_bgemm<true, true, false><<<grid, 256, 0, stream>>>(A, W, bias, R, C, N, K);
    else if (mode == MODE_GELU)
      k_bgemm<false, false, true><<<grid, 256, 0, stream>>>(A, W, nullptr, nullptr, C, N, K);
    else
      k_bgemm<false, true, false><<<grid, 256, 0, stream>>>(A, W, nullptr, R, C, N, K);
  };
  auto dft = [&](const float* A, float* S) {
    hipMemsetAsync(S, 0, 262144 * sizeof(float), stream);
    k_dft_mfma<<<256, 256, 0, stream>>>(A, fm_tw, S);
  };
  auto irdft = [&](const float* S, float* O, float scale) {
    k_irdft_mfma<<<512, 256, 0, stream>>>(S, gt_tw, O, scale);
  };
  auto decomp = [&](int tmode, const float* Z, float* Sout, float* T) {
    if (tmode == 0)      k_decomp2<0><<<NB * 128, 512, 0, stream>>>(Z, Sout, T);
    else if (tmode == 1) k_decomp2<1><<<NB * 128, 512, 0, stream>>>(Z, Sout, T);
    else                 k_decomp2<2><<<NB * 128, 512, 0, stream>>>(Z, Sout, T);
  };

  const int MR = NB * L;           // 16384 rows
  const int RW = 8192;             // FFN row chunk
  const size_t CH = (size_t)RW * Dm;

  // ---- Phase A: init + twiddles + embeddings ----
  k_gentw<<<2048, 256, 0, stream>>>(fm_tw, gt_tw);
  k_enc_mean<<<NB * NF, 256, 0, stream>>>(x_enc, mean_bf);
  k_init_decomp<<<(NB * L * NF + 255) / 256, 256, 0, stream>>>(x_enc, mean_bf, sinit, tinit);
  k_embed2<<<NB * 512, 256, 0, stream>>>(x_enc, enc_emb_W, S_enc);

  // ---- Phase B: encoder x2 (shared Fourier weights) ----
  for (int layer = 0; layer < 2; ++layer) {
    const float* Wl = enc_qkvo_W + (size_t)layer * 4 * Dm * Dm;
    const float* bl = enc_qkvo_b + (size_t)layer * 4 * Dm;
    gemm(S_enc, Wl, bl, nullptr, S_q, MR, Dm, Dm, MODE_BIAS);            // q proj
    dft(S_q, spec_q);
    k_cmul2<<<128, 256, 0, stream>>>(spec_q, enc_fourier_W, spec_o);
    irdft(spec_o, S_i, 1.0f / L);
    gemm(S_i, Wl + 3 * Dm * Dm, bl + 3 * Dm, S_enc, S_z, MR, Dm, Dm, MODE_BIAS_RES);
    decomp(0, S_z, S_x1, nullptr);
    for (int ch = 0; ch < 2; ++ch) {
      gemm(S_x1 + ch * CH, enc_ffn_W1 + (size_t)layer * DFF * Dm, nullptr, nullptr,
           S_q, RW, DFF, Dm, MODE_GELU);
      gemm(S_q, enc_ffn_W2 + (size_t)layer * Dm * DFF, nullptr, S_x1 + ch * CH,
           S_z + ch * CH, RW, Dm, DFF, MODE_RES);
    }
    decomp(0, S_z, S_enc, nullptr);
  }
  // my_layernorm(enc_out)
  k_ln<<<NB * L, 256, 0, stream>>>(S_enc, enc_norm_g, enc_norm_b, S_z);
  hipMemsetAsync(cm, 0, 2048 * sizeof(float), stream);
  k_colsum<<<dim3(NB, 2, 32), 256, 0, stream>>>(S_z, cm);
  k_sub<<<32768, 256, 0, stream>>>(S_z, cm, S_enc);

  // ---- Phase C: decoder ----
  k_embed2<<<NB * 512, 256, 0, stream>>>(sinit, dec_emb_W, S_dec);
  // self attention
  {
    const float* Wl = dec_qkvo_W;
    const float* bl = dec_qkvo_b;
    gemm(S_dec, Wl, bl, nullptr, S_q, MR, Dm, Dm, MODE_BIAS);
    dft(S_q, spec_q);
    k_cmul2<<<128, 256, 0, stream>>>(spec_q, dec_self_fourier_W, spec_o);
    irdft(spec_o, S_i, 1.0f / L);
    gemm(S_i, Wl + 3 * Dm * Dm, bl + 3 * Dm, S_dec, S_z, MR, Dm, Dm, MODE_BIAS_RES);
    decomp(1, S_z, S_x1, T_sum);
  }
  // cross attention
  {
    const float* Wl = dec_qkvo_W + (size_t)4 * Dm * Dm;
    const float* bl = dec_qkvo_b + 4 * Dm;
    gemm(S_x1, Wl, bl, nullptr, S_q, MR, Dm, Dm, MODE_BIAS);                       // q
    gemm(S_enc, Wl + Dm * Dm, bl + Dm, nullptr, S_i, MR, Dm, Dm, MODE_BIAS);       // k
    dft(S_q, spec_q);
    dft(S_i, spec_k);
    k_cross_s<<<NB * NH, 256, 0, stream>>>(spec_q, spec_k, spec_s);
    k_cross_o<<<NB * NH, 256, 0, stream>>>(spec_s, spec_k, spec_o2);
    k_cmul2<<<128, 256, 0, stream>>>(spec_o2, dec_cross_fourier_W, spec_o);
    irdft(spec_o, S_i, (1.0f / L) / (512.0f * 512.0f));
    gemm(S_i, Wl + 3 * Dm * Dm, bl + 3 * Dm, S_x1, S_z, MR, Dm, Dm, MODE_BIAS_RES);
    decomp(2, S_z, S_dec, T_sum);
  }
  // ffn
  for (int ch = 0; ch < 2; ++ch) {
    gemm(S_dec + ch * CH, dec_ffn_W1, nullptr, nullptr, S_q, RW, DFF, Dm, MODE_GELU);
    gemm(S_q, dec_ffn_W2, nullptr, S_dec + ch * CH, S_z + ch * CH, RW, Dm, DFF, MODE_RES);
  }
  decomp(2, S_z, S_x1, T_sum);
  // trend projection + final
  k_trendproj2<<<256, 256, 0, stream>>>(T_sum, dec_trend_proj_W, RT);
  k_ln<<<NB * L, 256, 0, stream>>>(S_x1, dec_norm_g, dec_norm_b, S_z);
  hipMemsetAsync(cm, 0, 2048 * sizeof(float), stream);
  k_colsum<<<dim3(NB, 2, 32), 256, 0, stream>>>(S_z, cm);
  k_final<<<NB * PRED, 256, 0, stream>>>(S_z, cm, final_W, final_b, tinit, RT, out);
}

// Round 6
// 1664.095 us; speedup vs baseline: 3.8750x; 1.7058x over previous
//
#include <hip/hip_runtime.h>
#include <hip/hip_bf16.h>
#include <math.h>

namespace {

constexpr int NB    = 4;
constexpr int L     = 4096;   // SEQ == LDEC
constexpr int PRED  = 2048;
constexpr int LABEL = 2048;
constexpr int NF    = 21;
constexpr int Dm    = 512;
constexpr int NH    = 8;
constexpr int NE    = 64;
constexpr int NM    = 64;
constexpr int DFF   = 2048;
constexpr float TWOPI = 6.283185307179586f;

typedef __attribute__((ext_vector_type(8))) short s16x8;
typedef __attribute__((ext_vector_type(4))) short s16x4;
typedef __attribute__((ext_vector_type(4))) float f32x4;

__device__ inline short f2b(float f) {
  __hip_bfloat16 h = __float2bfloat16(f);
  return __builtin_bit_cast(short, h);
}
__device__ inline float b2f(short s) {
  unsigned u = ((unsigned)(unsigned short)s) << 16;
  return __builtin_bit_cast(float, u);
}

// ---------------- fp32 -> bf16 bulk convert ----------------
__global__ void k_cvt(const float* __restrict__ src, short* __restrict__ dst, int n) {
  int i = (blockIdx.x * 256 + threadIdx.x) * 4;
  if (i >= n) return;
  f32x4 v = *(const f32x4*)(src + i);
  s16x4 p;
  p[0] = f2b(v[0]); p[1] = f2b(v[1]); p[2] = f2b(v[2]); p[3] = f2b(v[3]);
  *(s16x4*)(dst + i) = p;
}

// ---------------- init: column mean of x_enc over time ----------------
__global__ void k_enc_mean(const float* __restrict__ x, float* __restrict__ mean_bf) {
  int bf = blockIdx.x; int b = bf / NF, f = bf % NF;
  const float* p = x + (size_t)b * L * NF + f;
  float s = 0.f;
  for (int l = threadIdx.x; l < L; l += 256) s += p[(size_t)l * NF];
  __shared__ float red[256];
  red[threadIdx.x] = s; __syncthreads();
  for (int st = 128; st > 0; st >>= 1) {
    if (threadIdx.x < st) red[threadIdx.x] += red[threadIdx.x + st];
    __syncthreads();
  }
  if (threadIdx.x == 0) mean_bf[bf] = red[0] * (1.0f / L);
}

// ---------------- init decomp: seasonal_init / trend_init ----------------
__global__ void k_init_decomp(const float* __restrict__ x, const float* __restrict__ mean_bf,
                              float* __restrict__ sinit, float* __restrict__ tinit) {
  int idx = blockIdx.x * 256 + threadIdx.x;
  if (idx >= NB * L * NF) return;
  int f = idx % NF; int t = (idx / NF) % L; int b = idx / (NF * L);
  float sv, tv;
  if (t < LABEL) {
    int l = LABEL + t;
    float s = 0.f;
    #pragma unroll
    for (int j = -12; j <= 12; ++j) {
      int ll = l + j; ll = ll < 0 ? 0 : (ll > L - 1 ? L - 1 : ll);
      s += x[((size_t)b * L + ll) * NF + f];
    }
    float ma = s * (1.0f / 25.0f);
    sv = x[((size_t)b * L + l) * NF + f] - ma;
    tv = ma;
  } else { sv = 0.f; tv = mean_bf[b * NF + f]; }
  sinit[idx] = sv; tinit[idx] = tv;
}

// ---------------- embedding: circular conv3 (NF->Dm) + positional, dual out ----------------
__global__ __launch_bounds__(256) void k_embed2(const float* __restrict__ x,
                                                const float* __restrict__ W,
                                                float* __restrict__ out,
                                                short* __restrict__ outb) {
  int bid = blockIdx.x;
  int dt = bid & 7;
  int lt = (bid >> 3) & 63;
  int b  = bid >> 9;
  int l0 = lt << 6, d0 = dt << 6;
  __shared__ float xs[66][22];
  __shared__ float wt[63][68];
  int t = threadIdx.x;
  for (int i = t; i < 66 * 21; i += 256) {
    int r = i / 21, f = i - r * 21;
    int l = (l0 - 1 + r) & (L - 1);
    xs[r][f] = x[((size_t)b * L + l) * NF + f];
  }
  for (int i = t; i < 63 * 64; i += 256) {
    int k = i >> 6, dd = i & 63;
    wt[k][dd] = W[(size_t)(d0 + dd) * 63 + k];
  }
  __syncthreads();
  int tx = t & 15, ty = t >> 4;
  float acc[4][4] = {};
  #pragma unroll
  for (int f = 0; f < 21; ++f) {
    #pragma unroll
    for (int j = 0; j < 3; ++j) {
      int k = f * 3 + j;
      float xv[4], wv[4];
      #pragma unroll
      for (int i = 0; i < 4; ++i) xv[i] = xs[ty * 4 + i + j][f];
      #pragma unroll
      for (int jj = 0; jj < 4; ++jj) wv[jj] = wt[k][tx * 4 + jj];
      #pragma unroll
      for (int i = 0; i < 4; ++i)
        #pragma unroll
        for (int jj = 0; jj < 4; ++jj) acc[i][jj] += xv[i] * wv[jj];
    }
  }
  #pragma unroll
  for (int i = 0; i < 4; ++i) {
    int l = l0 + ty * 4 + i;
    #pragma unroll
    for (int jj = 0; jj < 4; ++jj) {
      int d = d0 + tx * 4 + jj;
      float dv = expf((float)(d & ~1) * (-9.210340371976184f / 512.0f));
      float ang = (float)l * dv;
      float pe = (d & 1) ? cosf(ang) : sinf(ang);
      float v = acc[i][jj] + pe;
      size_t o = ((size_t)b * L + l) * Dm + d;
      out[o] = v;
      outb[o] = f2b(v);
    }
  }
}

// ---------------- pure-bf16 MFMA GEMM: C = A @ W^T, 128x128 tile, BK=64 ----------------
// MODE 0: fp32 out, bias+res; 1: bf16 out, bias; 2: bf16 out, gelu; 3: fp32 out, res
template<int MODE>
__global__ __launch_bounds__(256) void k_bgemm2(const short* __restrict__ A,
                       const short* __restrict__ W,
                       const float* __restrict__ bias, const float* __restrict__ R,
                       void* __restrict__ Cv, int N, int K) {
  __shared__ __align__(16) short As[128 * 64];
  __shared__ __align__(16) short Bs[128 * 64];
  int nt = N >> 7;
  int n0 = (blockIdx.x % nt) << 7;
  int m0 = (int)(blockIdx.x / nt) << 7;
  int t = threadIdx.x;
  int lane = t & 63, v = t >> 6;
  int srow = t >> 1;
  int shalf = t & 1;
  const short* Ap = A + (size_t)(m0 + srow) * K + shalf * 32;
  const short* Wp = W + (size_t)(n0 + srow) * K + shalf * 32;
  int wsw[4];
  #pragma unroll
  for (int q = 0; q < 4; ++q)
    wsw[q] = srow * 64 + (((shalf * 4 + q) ^ (srow & 7)) << 3);
  int wr = (v >> 1) << 6, wc = (v & 1) << 6;
  int fr_a = wr + (lane & 15);
  int fr_b = wc + (lane & 15);
  int cbase = lane >> 4;
  f32x4 acc[4][4] = {};
  s16x8 ra[4], rb[4];
  #pragma unroll
  for (int q = 0; q < 4; ++q) {
    ra[q] = *(const s16x8*)(Ap + q * 8);
    rb[q] = *(const s16x8*)(Wp + q * 8);
  }
  for (int k0 = 0; k0 < K; k0 += 64) {
    if (k0) __syncthreads();
    #pragma unroll
    for (int q = 0; q < 4; ++q) {
      *(s16x8*)(As + wsw[q]) = ra[q];
      *(s16x8*)(Bs + wsw[q]) = rb[q];
    }
    __syncthreads();
    if (k0 + 64 < K) {
      #pragma unroll
      for (int q = 0; q < 4; ++q) {
        ra[q] = *(const s16x8*)(Ap + k0 + 64 + q * 8);
        rb[q] = *(const s16x8*)(Wp + k0 + 64 + q * 8);
      }
    }
    #pragma unroll
    for (int ks = 0; ks < 2; ++ks) {
      int c = cbase + ks * 4;
      s16x8 af[4], bf_[4];
      #pragma unroll
      for (int f = 0; f < 4; ++f) {
        int r1 = fr_a + f * 16;
        af[f] = *(const s16x8*)(As + r1 * 64 + ((c ^ (r1 & 7)) << 3));
        int r2 = fr_b + f * 16;
        bf_[f] = *(const s16x8*)(Bs + r2 * 64 + ((c ^ (r2 & 7)) << 3));
      }
      #pragma unroll
      for (int fm = 0; fm < 4; ++fm)
        #pragma unroll
        for (int fn = 0; fn < 4; ++fn)
          acc[fm][fn] = __builtin_amdgcn_mfma_f32_16x16x32_bf16(af[fm], bf_[fn], acc[fm][fn], 0, 0, 0);
    }
  }
  int em = m0 + wr + ((lane >> 4) << 2);
  int en = n0 + wc + (lane & 15);
  #pragma unroll
  for (int fm = 0; fm < 4; ++fm) {
    #pragma unroll
    for (int fn = 0; fn < 4; ++fn) {
      int n = en + fn * 16;
      #pragma unroll
      for (int r = 0; r < 4; ++r) {
        int m = em + fm * 16 + r;
        float vv = acc[fm][fn][r];
        if (MODE == 0 || MODE == 1) vv += bias[n];
        if (MODE == 2) vv = 0.5f * vv * (1.0f + erff(vv * 0.70710678118654752f));
        if (MODE == 0 || MODE == 3) {
          vv += R[(size_t)m * N + n];
          ((float*)Cv)[(size_t)m * N + n] = vv;
        } else {
          ((short*)Cv)[(size_t)m * N + n] = f2b(vv);
        }
      }
    }
  }
}

// ---------------- twiddle tables (bf16) ----------------
__global__ void k_gentw(short* __restrict__ fm, short* __restrict__ gt) {
  int idx = blockIdx.x * 256 + threadIdx.x;
  {
    int m2 = idx >> 12, l = idx & 4095;
    int m = m2 & 63;
    int ph = (m * l) & (L - 1);
    float sv, cv;
    __sincosf((float)ph * (TWOPI / L), &sv, &cv);
    fm[idx] = f2b((m2 < 64) ? cv : -sv);
  }
  {
    int l = idx >> 7, m2 = idx & 127;
    int m = m2 & 63;
    int ph = (m * l) & (L - 1);
    float sv, cv;
    __sincosf((float)ph * (TWOPI / L), &sv, &cv);
    float g;
    if (m2 == 0) g = 1.0f;
    else if (m2 == 64) g = 0.0f;
    else g = (m2 < 64) ? 2.0f * cv : -2.0f * sv;
    gt[idx] = f2b(g);
  }
}

// ---------------- MFMA forward DFT (bf16 input): S[b][c][m2] += sum_l A[b][l][c]*Fm[m2][l] ----------------
__global__ __launch_bounds__(256) void k_dft_mfma(const short* __restrict__ A,
                                                  const short* __restrict__ Fm,
                                                  float* __restrict__ S) {
  __shared__ __align__(16) short As[128 * 128];
  __shared__ __align__(16) short Bs[128 * 128];
  int bid = blockIdx.x;
  int kseg = bid & 15, ct = (bid >> 4) & 3, b = bid >> 6;
  int c0 = ct << 7;
  int lbase = kseg << 8;
  int t = threadIdx.x;
  int lane = t & 63, w = t >> 6;
  int wr = (w >> 1) << 6, wc = (w & 1) << 6;
  f32x4 acc[4][4] = {};
  const short* Ab = A + (size_t)b * L * Dm;

  for (int k0 = 0; k0 < 256; k0 += 128) {
    if (k0) __syncthreads();
    // stage A: transpose bf16 (l,c) -> LDS [c][l]
    #pragma unroll
    for (int it = 0; it < 4; ++it) {
      int s = it * 256 + t;
      int cq = (s & 31) << 2;
      int lq = (s >> 5) << 2;
      const short* base = Ab + (size_t)(lbase + k0 + lq) * Dm + c0 + cq;
      s16x4 r0 = *(const s16x4*)(base);
      s16x4 r1 = *(const s16x4*)(base + Dm);
      s16x4 r2 = *(const s16x4*)(base + 2 * Dm);
      s16x4 r3 = *(const s16x4*)(base + 3 * Dm);
      #pragma unroll
      for (int j = 0; j < 4; ++j) {
        int crow = cq + j;
        s16x4 p;
        p[0] = r0[j]; p[1] = r1[j]; p[2] = r2[j]; p[3] = r3[j];
        *(s16x4*)((char*)As + crow * 256 + ((lq * 2) ^ ((crow & 15) << 4))) = p;
      }
    }
    // stage B: Fm rows
    #pragma unroll
    for (int it = 0; it < 8; ++it) {
      int m = it * 16 + (t >> 4);
      int lb = (t & 15) * 8;
      s16x8 vv = *(const s16x8*)(Fm + (size_t)m * L + lbase + k0 + lb);
      *(s16x8*)((char*)Bs + m * 256 + ((lb * 2) ^ ((m & 15) << 4))) = vv;
    }
    __syncthreads();
    #pragma unroll
    for (int ks = 0; ks < 4; ++ks) {
      int kb = ks * 64 + ((lane >> 4) << 4);
      s16x8 af[4], bf_[4];
      #pragma unroll
      for (int f = 0; f < 4; ++f) {
        int fr = wr + (lane & 15) + f * 16;
        af[f] = *(const s16x8*)((const char*)As + fr * 256 + (kb ^ ((fr & 15) << 4)));
        int mr = wc + (lane & 15) + f * 16;
        bf_[f] = *(const s16x8*)((const char*)Bs + mr * 256 + (kb ^ ((mr & 15) << 4)));
      }
      #pragma unroll
      for (int fm = 0; fm < 4; ++fm)
        #pragma unroll
        for (int fn = 0; fn < 4; ++fn)
          acc[fm][fn] = __builtin_amdgcn_mfma_f32_16x16x32_bf16(af[fm], bf_[fn], acc[fm][fn], 0, 0, 0);
    }
  }
  float* Sb = S + (size_t)b * Dm * 128;
  int ec = c0 + wr + ((lane >> 4) << 2);
  int em = wc + (lane & 15);
  #pragma unroll
  for (int fm = 0; fm < 4; ++fm)
    #pragma unroll
    for (int fn = 0; fn < 4; ++fn)
      #pragma unroll
      for (int r = 0; r < 4; ++r)
        atomicAdd(&Sb[(size_t)(ec + fm * 16 + r) * 128 + em + fn * 16], acc[fm][fn][r]);
}

// ---------------- MFMA inverse DFT: O[b][c][l] = scale * sum_m S[b][c][m]*Gt[l][m], bf16 out ----------------
__global__ __launch_bounds__(256) void k_irdft_mfma(const float* __restrict__ S,
                                                    const short* __restrict__ Gt,
                                                    short* __restrict__ O, float scale) {
  __shared__ __align__(16) short As[128 * 128];
  __shared__ __align__(16) short Bs[128 * 128];
  int bid = blockIdx.x;
  int lt = bid & 31, ct = (bid >> 5) & 3, b = bid >> 7;
  int c0 = ct << 7;
  int l0t = lt << 7;
  int t = threadIdx.x;
  int lane = t & 63, w = t >> 6;
  int wr = (w >> 1) << 6, wc = (w & 1) << 6;
  f32x4 acc[4][4] = {};
  #pragma unroll
  for (int it = 0; it < 8; ++it) {
    int c = it * 16 + (t >> 4);
    int me = (t & 15) * 8;
    const float* sp = S + ((size_t)b * Dm + c0 + c) * 128 + me;
    f32x4 v0 = *(const f32x4*)sp;
    f32x4 v1 = *(const f32x4*)(sp + 4);
    s16x8 p;
    p[0]=f2b(v0[0]); p[1]=f2b(v0[1]); p[2]=f2b(v0[2]); p[3]=f2b(v0[3]);
    p[4]=f2b(v1[0]); p[5]=f2b(v1[1]); p[6]=f2b(v1[2]); p[7]=f2b(v1[3]);
    *(s16x8*)((char*)As + c * 256 + ((me * 2) ^ ((c & 15) << 4))) = p;
  }
  #pragma unroll
  for (int it = 0; it < 8; ++it) {
    int l = it * 16 + (t >> 4);
    int me = (t & 15) * 8;
    s16x8 vv = *(const s16x8*)(Gt + (size_t)(l0t + l) * 128 + me);
    *(s16x8*)((char*)Bs + l * 256 + ((me * 2) ^ ((l & 15) << 4))) = vv;
  }
  __syncthreads();
  #pragma unroll
  for (int ks = 0; ks < 4; ++ks) {
    int kb = ks * 64 + ((lane >> 4) << 4);
    s16x8 af[4], bf_[4];
    #pragma unroll
    for (int f = 0; f < 4; ++f) {
      int fr = wr + (lane & 15) + f * 16;
      af[f] = *(const s16x8*)((const char*)As + fr * 256 + (kb ^ ((fr & 15) << 4)));
      int lr = wc + (lane & 15) + f * 16;
      bf_[f] = *(const s16x8*)((const char*)Bs + lr * 256 + (kb ^ ((lr & 15) << 4)));
    }
    #pragma unroll
    for (int fm = 0; fm < 4; ++fm)
      #pragma unroll
      for (int fn = 0; fn < 4; ++fn)
        acc[fm][fn] = __builtin_amdgcn_mfma_f32_16x16x32_bf16(af[fm], bf_[fn], acc[fm][fn], 0, 0, 0);
  }
  short* Ob = O + (size_t)b * Dm * L;
  int ec = c0 + wr + ((lane >> 4) << 2);
  int el = l0t + wc + (lane & 15);
  #pragma unroll
  for (int fm = 0; fm < 4; ++fm)
    #pragma unroll
    for (int fn = 0; fn < 4; ++fn)
      #pragma unroll
      for (int r = 0; r < 4; ++r)
        Ob[(size_t)(ec + fm * 16 + r) * L + el + fn * 16] = f2b(scale * acc[fm][fn][r]);
}

// ---------------- per-mode complex channel mix ----------------
__global__ __launch_bounds__(256) void k_cmul2(const float* __restrict__ S, const float* __restrict__ Wf,
                                               float* __restrict__ O) {
  __shared__ float q[64 * 128];
  int bid = blockIdx.x;
  int og = bid & 3, h = (bid >> 2) & 7, b = bid >> 5;
  int t = threadIdx.x;
  const float* Sb = S + ((size_t)b * Dm + h * NE) * 128;
  for (int i = t; i < 8192; i += 256) q[i] = Sb[i];
  __syncthreads();
  int o = og * 16 + (t >> 4);
  int m0 = (t & 15) * 4;
  float ar[4] = {}, ai[4] = {};
  for (int i = 0; i < 64; ++i) {
    const float* wrow = Wf + (((size_t)h * 64 + i) * 64 + o) * 128 + m0 * 2;
    float wv[8];
    *(f32x4*)wv = *(const f32x4*)wrow;
    *(f32x4*)(wv + 4) = *(const f32x4*)(wrow + 4);
    const float* qi_ = q + i * 128;
    #pragma unroll
    for (int k = 0; k < 4; ++k) {
      float qr = qi_[m0 + k], qim = qi_[64 + m0 + k];
      float wr = wv[2 * k], wi = wv[2 * k + 1];
      ar[k] += qr * wr - qim * wi;
      ai[k] += qr * wi + qim * wr;
    }
  }
  float* Ob = O + ((size_t)b * Dm + h * NE + o) * 128;
  f32x4 vr, vi;
  #pragma unroll
  for (int k = 0; k < 4; ++k) { vr[k] = ar[k]; vi[k] = ai[k]; }
  *(f32x4*)(Ob + m0) = vr;
  *(f32x4*)(Ob + 64 + m0) = vi;
}

// ---------------- cross: s[x,y] = ctanh(sum_e qf[e,x]*kf[e,y]) ----------------
__global__ void k_cross_s(const float* __restrict__ Sq, const float* __restrict__ Sk,
                          float* __restrict__ Sout) {
  int bh = blockIdx.x;
  int b = bh >> 3, h = bh & 7;
  __shared__ float Qr[64][64], Qi[64][64], Kr[64][64], Ki[64][64];
  int t = threadIdx.x;
  const float* qb = Sq + ((size_t)b * Dm + h * NE) * 128;
  const float* kb = Sk + ((size_t)b * Dm + h * NE) * 128;
  for (int idx = t; idx < 4096; idx += 256) {
    int e = idx >> 6, x = idx & 63;
    Qr[e][x] = qb[e * 128 + x];
    Qi[e][x] = qb[e * 128 + 64 + x];
    Kr[e][x] = kb[e * 128 + x];
    Ki[e][x] = kb[e * 128 + 64 + x];
  }
  __syncthreads();
  int tx = t & 15, ty = t >> 4;
  float ar[4][4] = {}, ai[4][4] = {};
  for (int e = 0; e < 64; ++e) {
    float qr[4], qi[4], kr[4], ki[4];
    #pragma unroll
    for (int i = 0; i < 4; ++i) { qr[i] = Qr[e][(ty << 2) + i]; qi[i] = Qi[e][(ty << 2) + i]; }
    #pragma unroll
    for (int j = 0; j < 4; ++j) { kr[j] = Kr[e][(tx << 2) + j]; ki[j] = Ki[e][(tx << 2) + j]; }
    #pragma unroll
    for (int i = 0; i < 4; ++i)
      #pragma unroll
      for (int j = 0; j < 4; ++j) {
        ar[i][j] += qr[i] * kr[j] - qi[i] * ki[j];
        ai[i][j] += qr[i] * ki[j] + qi[i] * kr[j];
      }
  }
  float* sp = Sout + (size_t)bh * 4096 * 2;
  #pragma unroll
  for (int i = 0; i < 4; ++i)
    #pragma unroll
    for (int j = 0; j < 4; ++j) {
      int x = (ty << 2) + i, y = (tx << 2) + j;
      float a = ar[i][j], bb = ai[i][j];
      float th = tanhf(a);
      float u = tanf(bb);
      float re, im;
      if (fabsf(u) <= 1.0f) {
        float dn = 1.0f + th * th * u * u;
        re = th * (1.0f + u * u) / dn;
        im = u * (1.0f - th * th) / dn;
      } else {
        float iu = 1.0f / u;
        float dn = iu * iu + th * th;
        re = th * (iu * iu + 1.0f) / dn;
        im = iu * (1.0f - th * th) / dn;
      }
      sp[(x * 64 + y) * 2]     = re;
      sp[(x * 64 + y) * 2 + 1] = im;
    }
}

// ---------------- cross: o[e,x] = sum_y s[x,y]*kf[e,y] ----------------
__global__ void k_cross_o(const float* __restrict__ Sin, const float* __restrict__ Sk,
                          float* __restrict__ O2) {
  int bh = blockIdx.x;
  int b = bh >> 3, h = bh & 7;
  __shared__ float SrT[64][64], SiT[64][64], KrT[64][64], KiT[64][64];
  int t = threadIdx.x;
  const float* sp = Sin + (size_t)bh * 8192;
  const float* kb = Sk + ((size_t)b * Dm + h * NE) * 128;
  for (int idx = t; idx < 4096; idx += 256) {
    int r = idx >> 6, c = idx & 63;
    SrT[c][r] = sp[idx * 2];
    SiT[c][r] = sp[idx * 2 + 1];
    KrT[c][r] = kb[r * 128 + c];
    KiT[c][r] = kb[r * 128 + 64 + c];
  }
  __syncthreads();
  int tx = t & 15, ty = t >> 4;
  float ar[4][4] = {}, ai[4][4] = {};
  for (int y = 0; y < 64; ++y) {
    float kr[4], ki[4], sr[4], si[4];
    #pragma unroll
    for (int i = 0; i < 4; ++i) { kr[i] = KrT[y][(ty << 2) + i]; ki[i] = KiT[y][(ty << 2) + i]; }
    #pragma unroll
    for (int j = 0; j < 4; ++j) { sr[j] = SrT[y][(tx << 2) + j]; si[j] = SiT[y][(tx << 2) + j]; }
    #pragma unroll
    for (int i = 0; i < 4; ++i)
      #pragma unroll
      for (int j = 0; j < 4; ++j) {
        ar[i][j] += sr[j] * kr[i] - si[j] * ki[i];
        ai[i][j] += sr[j] * ki[i] + si[j] * kr[i];
      }
  }
  float* ob = O2 + ((size_t)b * Dm + h * NE) * 128;
  #pragma unroll
  for (int i = 0; i < 4; ++i)
    #pragma unroll
    for (int j = 0; j < 4; ++j) {
      int e = (ty << 2) + i, x = (tx << 2) + j;
      ob[e * 128 + x]      = ar[i][j];
      ob[e * 128 + 64 + x] = ai[i][j];
    }
}

// ---------------- series_decomp sliding window, dual out ----------------
template<int TMODE> // 0 none, 1 write trend, 2 add trend
__global__ __launch_bounds__(512) void k_decomp3(const float* __restrict__ Z, float* __restrict__ Sout,
                          short* __restrict__ Sb, float* __restrict__ T) {
  int b = blockIdx.x >> 7;
  int l0 = (blockIdx.x & 127) << 5;
  int d = threadIdx.x;
  const float* zb = Z + (size_t)b * L * Dm + d;
  float s = 0.f;
  #pragma unroll
  for (int j = -12; j <= 12; ++j) {
    int ll = l0 + j; ll = ll < 0 ? 0 : ll;
    s += zb[(size_t)ll * Dm];
  }
  for (int i = 0; i < 32; ++i) {
    int l = l0 + i;
    float ma = s * (1.0f / 25.0f);
    size_t idx = ((size_t)b * L + l) * Dm + d;
    float se = zb[(size_t)l * Dm] - ma;
    Sout[idx] = se;
    Sb[idx] = f2b(se);
    if (TMODE == 1) T[idx] = ma;
    else if (TMODE == 2) T[idx] += ma;
    int la = l + 13; la = la > L - 1 ? L - 1 : la;
    int lr = l - 12; lr = lr < 0 ? 0 : lr;
    s += zb[(size_t)la * Dm] - zb[(size_t)lr * Dm];
  }
}

// ---------------- row LayerNorm over Dm ----------------
__global__ void k_ln(const float* __restrict__ X, const float* __restrict__ g,
                     const float* __restrict__ be, float* __restrict__ Y) {
  int row = blockIdx.x;
  const float* x = X + (size_t)row * Dm;
  int t = threadIdx.x;
  float v0 = x[t], v1 = x[t + 256];
  float s = v0 + v1;
  __shared__ float red[4];
  #pragma unroll
  for (int off = 32; off > 0; off >>= 1) s += __shfl_down(s, off);
  int wid = t >> 6, lane = t & 63;
  if (lane == 0) red[wid] = s;
  __syncthreads();
  float mu = (red[0] + red[1] + red[2] + red[3]) * (1.0f / Dm);
  float e0 = v0 - mu, e1 = v1 - mu;
  float s2 = e0 * e0 + e1 * e1;
  #pragma unroll
  for (int off = 32; off > 0; off >>= 1) s2 += __shfl_down(s2, off);
  __syncthreads();
  if (lane == 0) red[wid] = s2;
  __syncthreads();
  float var = (red[0] + red[1] + red[2] + red[3]) * (1.0f / Dm);
  float rstd = rsqrtf(var + 1e-5f);
  float* y = Y + (size_t)row * Dm;
  y[t]       = e0 * rstd * g[t] + be[t];
  y[t + 256] = e1 * rstd * g[t + 256] + be[t + 256];
}

// ---------------- column sums over time ----------------
__global__ void k_colsum(const float* __restrict__ X, float* __restrict__ cm) {
  int b = blockIdx.x;
  int d = blockIdx.y * 256 + threadIdx.x;
  int lc = blockIdx.z;
  const float* x = X + ((size_t)b * L + (size_t)lc * 128) * Dm + d;
  float s = 0.f;
  for (int i = 0; i < 128; ++i) s += x[(size_t)i * Dm];
  atomicAdd(&cm[b * Dm + d], s);
}

// my_layernorm finish: bf16 out only (consumed by cross k-proj GEMM)
__global__ void k_sub2(const float* __restrict__ X, const float* __restrict__ cm,
                       short* __restrict__ Y) {
  size_t idx = (size_t)blockIdx.x * 256 + threadIdx.x;
  int d = (int)(idx & (Dm - 1));
  int b = (int)(idx >> 21);
  Y[idx] = f2b(X[idx] - cm[b * Dm + d] * (1.0f / L));
}

// ---------------- trend projection: circular conv3 (Dm -> NF), W LDS [d][63] bf16 swizzled ----------------
__global__ __launch_bounds__(256) void k_trendproj3(const float* __restrict__ T,
                                                    const float* __restrict__ Wp,
                                                    float* __restrict__ RT) {
  __shared__ short wlds[512 * 64];  // 64 KiB
  int t = threadIdx.x;
  for (int i = t; i < NF * 512 * 3; i += 256) {
    int f = i / 1536, rem = i - f * 1536;
    int d = rem / 3, j = rem - d * 3;
    int s = f * 3 + j;
    int dst = d * 64 + (((s >> 3) ^ (d & 7)) << 3) + (s & 7);
    wlds[dst] = f2b(Wp[i]);
  }
  __syncthreads();
  int b = blockIdx.x >> 8;
  int g0 = (blockIdx.x & 255) << 4;
  int v = t >> 6, lane = t & 63;
  const float* Tb = T + (size_t)b * L * Dm;
  for (int rr = 0; rr < 4; ++rr) {
    int l = g0 + v * 4 + rr;
    int lm = (l - 1) & (L - 1), lp = (l + 1) & (L - 1);
    float acc[NF];
    #pragma unroll
    for (int f = 0; f < NF; ++f) acc[f] = 0.f;
    #pragma unroll
    for (int k = 0; k < 8; ++k) {
      int d = lane + k * 64;
      float t0 = Tb[(size_t)lm * Dm + d];
      float t1 = Tb[(size_t)l  * Dm + d];
      float t2 = Tb[(size_t)lp * Dm + d];
      const short* wrow = wlds + d * 64;
      int dsw = d & 7;
      #pragma unroll
      for (int c = 0; c < 8; ++c) {
        s16x8 wv = *(const s16x8*)(wrow + ((c ^ dsw) << 3));
        #pragma unroll
        for (int e = 0; e < 8; ++e) {
          int s = c * 8 + e;
          if (s < 63) {
            int f = s / 3, j = s - (s / 3) * 3;
            float wgt = b2f(wv[e]);
            acc[f] += (j == 0 ? t0 : (j == 1 ? t1 : t2)) * wgt;
          }
        }
      }
    }
    #pragma unroll
    for (int f = 0; f < NF; ++f) {
      float s = acc[f];
      #pragma unroll
      for (int off = 32; off > 0; off >>= 1) s += __shfl_xor(s, off);
      acc[f] = s;
    }
    if (lane == 0) {
      float* rp = RT + ((size_t)b * L + l) * NF;
      #pragma unroll
      for (int f = 0; f < NF; ++f) rp[f] = acc[f];
    }
  }
}

// ---------------- final: out = tinit + RT + my_ln(x) @ Wf^T + bf ----------------
__global__ void k_final(const float* __restrict__ X, const float* __restrict__ cm,
                        const float* __restrict__ Wf, const float* __restrict__ bf,
                        const float* __restrict__ tinit, const float* __restrict__ RT,
                        float* __restrict__ out) {
  int bt = blockIdx.x; int b = bt / PRED, tt = bt % PRED;
  int l = LABEL + tt;
  __shared__ float row[512];
  __shared__ float partial[NF][9];
  int t = threadIdx.x;
  const float* x = X + ((size_t)b * L + l) * Dm;
  const float* c = cm + b * Dm;
  row[t]       = x[t]       - c[t]       * (1.0f / L);
  row[t + 256] = x[t + 256] - c[t + 256] * (1.0f / L);
  __syncthreads();
  if (t < 168) {
    int f = t >> 3, p = t & 7;
    const float* w = Wf + (size_t)f * Dm + p * 64;
    float s = 0.f;
    #pragma unroll
    for (int q = 0; q < 64; ++q) s += row[p * 64 + q] * w[q];
    partial[f][p] = s;
  }
  __syncthreads();
  if (t < NF) {
    float s = bf[t];
    #pragma unroll
    for (int p = 0; p < 8; ++p) s += partial[t][p];
    size_t src = ((size_t)b * L + l) * NF + t;
    out[((size_t)b * PRED + tt) * NF + t] = s + tinit[src] + RT[src];
  }
}

} // namespace

extern "C" void kernel_launch(void* const* d_in, const int* in_sizes, int n_in,
                              void* d_out, int out_size, void* d_ws, size_t ws_size,
                              hipStream_t stream) {
  (void)in_sizes; (void)n_in; (void)out_size; (void)ws_size;
  const float* x_enc              = (const float*)d_in[0];
  const float* enc_emb_W          = (const float*)d_in[3];
  const float* dec_emb_W          = (const float*)d_in[4];
  const float* enc_qkvo_W         = (const float*)d_in[5];
  const float* enc_qkvo_b         = (const float*)d_in[6];
  const float* enc_ffn_W1         = (const float*)d_in[7];
  const float* enc_ffn_W2         = (const float*)d_in[8];
  const float* enc_fourier_W      = (const float*)d_in[9];
  const float* enc_norm_g         = (const float*)d_in[10];
  const float* enc_norm_b         = (const float*)d_in[11];
  const float* dec_qkvo_W         = (const float*)d_in[12];
  const float* dec_qkvo_b         = (const float*)d_in[13];
  const float* dec_ffn_W1         = (const float*)d_in[14];
  const float* dec_ffn_W2         = (const float*)d_in[15];
  const float* dec_self_fourier_W = (const float*)d_in[16];
  const float* dec_cross_fourier_W= (const float*)d_in[17];
  const float* dec_trend_proj_W   = (const float*)d_in[18];
  const float* dec_norm_g         = (const float*)d_in[19];
  const float* dec_norm_b         = (const float*)d_in[20];
  const float* final_W            = (const float*)d_in[21];
  const float* final_b            = (const float*)d_in[22];
  float* out = (float*)d_out;

  // ---- workspace layout: 54,249,600 floats = 207 MiB (round-4's proven 236 MiB bound) ----
  float* ws = (float*)d_ws;
  const size_t SZ = (size_t)NB * L * Dm;     // 8,388,608
  float* S_x   = ws;                         // enc residual, later decoder x
  float* S_dec = ws + SZ;                    // dec residual
  float* S_z   = ws + 2 * SZ;                // gemm / ln scratch
  float* T_sum = ws + 3 * SZ;                // trend accumulation
  short* act   = (short*)(ws + 4 * SZ);      // 2*SZ shorts: H1 | H2
  short* S_qb  = act;                        // H1
  short* S_xb  = act + SZ;                   // H2
  short* H16   = act;                        // FFN hidden 8192x2048 (H1+H2)
  short* S_eb  = (short*)(ws + 5 * SZ);      // SZ shorts: layer-input / FFN-x / enc-ln bf16
  short* W16   = (short*)(ws + 5 * SZ + SZ / 2);  // 10,485,760 shorts
  float* sm = ws + 5 * SZ + SZ / 2 + 5242880;
  float* spec_q  = sm; sm += 262144;
  float* spec_k  = sm; sm += 262144;
  float* spec_o  = sm; sm += 262144;
  float* spec_o2 = sm; sm += 262144;
  float* spec_s  = sm; sm += 262144;
  float* mean_bf = sm; sm += 128;
  float* cm      = sm; sm += 2048;
  float* sinit   = sm; sm += (size_t)NB * L * NF;
  float* tinit   = sm; sm += (size_t)NB * L * NF;
  float* RT      = sm; sm += (size_t)NB * L * NF;
  short* fm_tw   = (short*)sm; sm += 262144;
  short* gt_tw   = (short*)sm; sm += 262144;

  short* w16_eq = W16;            // enc qkvo
  short* w16_e1 = W16 + 2097152;  // enc ffn1
  short* w16_e2 = W16 + 4194304;  // enc ffn2
  short* w16_dq = W16 + 6291456;  // dec qkvo
  short* w16_d1 = W16 + 8388608;
  short* w16_d2 = W16 + 9437184;

  auto cvt = [&](const float* s, short* d, int n) {
    k_cvt<<<(n / 4 + 255) / 256, 256, 0, stream>>>(s, d, n);
  };
  auto gemm = [&](int mode, const short* A, const short* Wt, const float* bias,
                  const float* R, void* C, int Mr, int N, int K) {
    dim3 grid((unsigned)((Mr >> 7) * (N >> 7)));
    if (mode == 0)      k_bgemm2<0><<<grid, 256, 0, stream>>>(A, Wt, bias, R, C, N, K);
    else if (mode == 1) k_bgemm2<1><<<grid, 256, 0, stream>>>(A, Wt, bias, R, C, N, K);
    else if (mode == 2) k_bgemm2<2><<<grid, 256, 0, stream>>>(A, Wt, bias, R, C, N, K);
    else                k_bgemm2<3><<<grid, 256, 0, stream>>>(A, Wt, bias, R, C, N, K);
  };
  auto dft = [&](const short* A, float* S) {
    hipMemsetAsync(S, 0, 262144 * sizeof(float), stream);
    k_dft_mfma<<<256, 256, 0, stream>>>(A, fm_tw, S);
  };
  auto irdft = [&](const float* S, short* O, float scale) {
    k_irdft_mfma<<<512, 256, 0, stream>>>(S, gt_tw, O, scale);
  };
  auto decomp = [&](int tmode, const float* Z, float* Sout, short* Sb, float* T) {
    if (tmode == 0)      k_decomp3<0><<<NB * 128, 512, 0, stream>>>(Z, Sout, Sb, T);
    else if (tmode == 1) k_decomp3<1><<<NB * 128, 512, 0, stream>>>(Z, Sout, Sb, T);
    else                 k_decomp3<2><<<NB * 128, 512, 0, stream>>>(Z, Sout, Sb, T);
  };

  const int MR = NB * L;             // 16384
  const int RW = 8192;               // FFN row chunk
  const size_t CH  = (size_t)RW * Dm; // floats / shorts per chunk
  const int QQ = 262144;             // 512*512

  // ---- Phase A: weights->bf16, twiddles, init, embed ----
  k_gentw<<<2048, 256, 0, stream>>>(fm_tw, gt_tw);
  cvt(enc_qkvo_W, w16_eq, 2097152);
  cvt(enc_ffn_W1, w16_e1, 2097152);
  cvt(enc_ffn_W2, w16_e2, 2097152);
  cvt(dec_qkvo_W, w16_dq, 2097152);
  cvt(dec_ffn_W1, w16_d1, 1048576);
  cvt(dec_ffn_W2, w16_d2, 1048576);
  k_enc_mean<<<NB * NF, 256, 0, stream>>>(x_enc, mean_bf);
  k_init_decomp<<<(NB * L * NF + 255) / 256, 256, 0, stream>>>(x_enc, mean_bf, sinit, tinit);
  k_embed2<<<NB * 512, 256, 0, stream>>>(x_enc, enc_emb_W, S_x, S_eb);

  // ---- Phase B: encoder x2 (shared Fourier weights) ----
  for (int layer = 0; layer < 2; ++layer) {
    const short* Wl = w16_eq + (size_t)layer * 4 * QQ;
    const float* bl = enc_qkvo_b + (size_t)layer * 4 * Dm;
    gemm(1, S_eb, Wl, bl, nullptr, S_qb, MR, Dm, Dm);                 // q proj -> H1
    dft(S_qb, spec_q);
    k_cmul2<<<128, 256, 0, stream>>>(spec_q, enc_fourier_W, spec_o);
    irdft(spec_o, S_xb, 1.0f / L);                                    // attn out -> H2
    gemm(0, S_xb, Wl + 3 * QQ, bl + 3 * Dm, S_x, S_z, MR, Dm, Dm);    // o proj + res
    decomp(0, S_z, S_x, S_eb, nullptr);                               // x -> S_x fp32, S_eb bf16
    for (int ch = 0; ch < 2; ++ch) {
      gemm(2, S_eb + (size_t)ch * CH, w16_e1 + (size_t)layer * DFF * Dm, nullptr, nullptr,
           H16, RW, DFF, Dm);                                         // gelu hidden -> act full
      gemm(3, H16, w16_e2 + (size_t)layer * Dm * DFF, nullptr, S_x + ch * CH,
           S_z + ch * CH, RW, Dm, DFF);                               // + residual x
    }
    decomp(0, S_z, S_x, S_eb, nullptr);                               // next layer input
  }
  // my_layernorm(enc_out) -> bf16 in S_eb; S_x fp32 becomes free
  k_ln<<<NB * L, 256, 0, stream>>>(S_x, enc_norm_g, enc_norm_b, S_z);
  hipMemsetAsync(cm, 0, 2048 * sizeof(float), stream);
  k_colsum<<<dim3(NB, 2, 32), 256, 0, stream>>>(S_z, cm);
  k_sub2<<<32768, 256, 0, stream>>>(S_z, cm, S_eb);

  // ---- Phase C: decoder ----
  k_embed2<<<NB * 512, 256, 0, stream>>>(sinit, dec_emb_W, S_dec, S_xb);  // embed bf16 -> H2
  // self attention
  {
    const short* Wl = w16_dq;
    const float* bl = dec_qkvo_b;
    gemm(1, S_xb, Wl, bl, nullptr, S_qb, MR, Dm, Dm);                 // q from embed
    dft(S_qb, spec_q);
    k_cmul2<<<128, 256, 0, stream>>>(spec_q, dec_self_fourier_W, spec_o);
    irdft(spec_o, S_xb, 1.0f / L);                                    // H2 (embed bf16 dead)
    gemm(0, S_xb, Wl + 3 * QQ, bl + 3 * Dm, S_dec, S_z, MR, Dm, Dm);  // o proj + embed res
    decomp(1, S_z, S_x, S_xb, T_sum);                                 // x1 -> S_x fp32, H2 bf16
  }
  // cross attention
  {
    const short* Wl = w16_dq + 4 * QQ;
    const float* bl = dec_qkvo_b + 4 * Dm;
    gemm(1, S_xb, Wl, bl, nullptr, S_qb, MR, Dm, Dm);                 // q from x1 -> H1
    gemm(1, S_eb, Wl + QQ, bl + Dm, nullptr, S_xb, MR, Dm, Dm);       // k from enc -> H2
    dft(S_qb, spec_q);
    dft(S_xb, spec_k);
    k_cross_s<<<NB * NH, 256, 0, stream>>>(spec_q, spec_k, spec_s);
    k_cross_o<<<NB * NH, 256, 0, stream>>>(spec_s, spec_k, spec_o2);
    k_cmul2<<<128, 256, 0, stream>>>(spec_o2, dec_cross_fourier_W, spec_o);
    irdft(spec_o, S_qb, (1.0f / L) / (512.0f * 512.0f));              // H1 (q spec dead)
    gemm(0, S_qb, Wl + 3 * QQ, bl + 3 * Dm, S_x, S_z, MR, Dm, Dm);    // o proj + x1 res
    decomp(2, S_z, S_dec, S_eb, T_sum);                               // x2 -> S_dec fp32, S_eb bf16
  }
  // ffn (hidden = act full; x bf16 in S_eb)
  for (int ch = 0; ch < 2; ++ch) {
    gemm(2, S_eb + (size_t)ch * CH, w16_d1, nullptr, nullptr, H16, RW, DFF, Dm);
    gemm(3, H16, w16_d2, nullptr, S_dec + ch * CH, S_z + ch * CH, RW, Dm, DFF);
  }
  decomp(2, S_z, S_x, S_eb, T_sum);                                   // final x -> S_x
  // trend projection + final
  k_trendproj3<<<NB * 256, 256, 0, stream>>>(T_sum, dec_trend_proj_W, RT);
  k_ln<<<NB * L, 256, 0, stream>>>(S_x, dec_norm_g, dec_norm_b, S_z);
  hipMemsetAsync(cm, 0, 2048 * sizeof(float), stream);
  k_colsum<<<dim3(NB, 2, 32), 256, 0, stream>>>(S_z, cm);
  k_final<<<NB * PRED, 256, 0, stream>>>(S_z, cm, final_W, final_b, tinit, RT, out);
}

// Round 7
// 1595.483 us; speedup vs baseline: 4.0416x; 1.0430x over previous
//
#include <hip/hip_runtime.h>
#include <hip/hip_bf16.h>
#include <math.h>

namespace {

constexpr int NB    = 4;
constexpr int L     = 4096;   // SEQ == LDEC
constexpr int PRED  = 2048;
constexpr int LABEL = 2048;
constexpr int NF    = 21;
constexpr int Dm    = 512;
constexpr int NH    = 8;
constexpr int NE    = 64;
constexpr int NM    = 64;
constexpr int DFF   = 2048;
constexpr float TWOPI = 6.283185307179586f;

typedef __attribute__((ext_vector_type(8))) short s16x8;
typedef __attribute__((ext_vector_type(4))) short s16x4;
typedef __attribute__((ext_vector_type(4))) float f32x4;

__device__ inline short f2b(float f) {
  __hip_bfloat16 h = __float2bfloat16(f);
  return __builtin_bit_cast(short, h);
}
__device__ inline float b2f(short s) {
  unsigned u = ((unsigned)(unsigned short)s) << 16;
  return __builtin_bit_cast(float, u);
}

// ---------------- fp32 -> bf16 bulk convert ----------------
__global__ void k_cvt(const float* __restrict__ src, short* __restrict__ dst, int n) {
  int i = (blockIdx.x * 256 + threadIdx.x) * 4;
  if (i >= n) return;
  f32x4 v = *(const f32x4*)(src + i);
  s16x4 p;
  p[0] = f2b(v[0]); p[1] = f2b(v[1]); p[2] = f2b(v[2]); p[3] = f2b(v[3]);
  *(s16x4*)(dst + i) = p;
}

// ---------------- trend-proj weight pack: Wp[21][512][3] -> Wt3[3][32][512] bf16 (zero-pad) ----------------
__global__ void k_prepw(const float* __restrict__ Wp, short* __restrict__ Wt3) {
  int i = blockIdx.x * 256 + threadIdx.x;
  if (i >= 3 * 32 * 512) return;
  int d = i & 511, n = (i >> 9) & 31, j = i >> 14;
  float v = (n < NF) ? Wp[(size_t)n * 1536 + d * 3 + j] : 0.f;
  Wt3[i] = f2b(v);
}

// ---------------- init: column mean of x_enc over time ----------------
__global__ void k_enc_mean(const float* __restrict__ x, float* __restrict__ mean_bf) {
  int bf = blockIdx.x; int b = bf / NF, f = bf % NF;
  const float* p = x + (size_t)b * L * NF + f;
  float s = 0.f;
  for (int l = threadIdx.x; l < L; l += 256) s += p[(size_t)l * NF];
  __shared__ float red[256];
  red[threadIdx.x] = s; __syncthreads();
  for (int st = 128; st > 0; st >>= 1) {
    if (threadIdx.x < st) red[threadIdx.x] += red[threadIdx.x + st];
    __syncthreads();
  }
  if (threadIdx.x == 0) mean_bf[bf] = red[0] * (1.0f / L);
}

// ---------------- init decomp: seasonal_init / trend_init ----------------
__global__ void k_init_decomp(const float* __restrict__ x, const float* __restrict__ mean_bf,
                              float* __restrict__ sinit, float* __restrict__ tinit) {
  int idx = blockIdx.x * 256 + threadIdx.x;
  if (idx >= NB * L * NF) return;
  int f = idx % NF; int t = (idx / NF) % L; int b = idx / (NF * L);
  float sv, tv;
  if (t < LABEL) {
    int l = LABEL + t;
    float s = 0.f;
    #pragma unroll
    for (int j = -12; j <= 12; ++j) {
      int ll = l + j; ll = ll < 0 ? 0 : (ll > L - 1 ? L - 1 : ll);
      s += x[((size_t)b * L + ll) * NF + f];
    }
    float ma = s * (1.0f / 25.0f);
    sv = x[((size_t)b * L + l) * NF + f] - ma;
    tv = ma;
  } else { sv = 0.f; tv = mean_bf[b * NF + f]; }
  sinit[idx] = sv; tinit[idx] = tv;
}

// ---------------- embedding: circular conv3 (NF->Dm) + positional, dual out ----------------
__global__ __launch_bounds__(256) void k_embed2(const float* __restrict__ x,
                                                const float* __restrict__ W,
                                                float* __restrict__ out,
                                                short* __restrict__ outb) {
  int bid = blockIdx.x;
  int dt = bid & 7;
  int lt = (bid >> 3) & 63;
  int b  = bid >> 9;
  int l0 = lt << 6, d0 = dt << 6;
  __shared__ float xs[66][22];
  __shared__ float wt[63][68];
  int t = threadIdx.x;
  for (int i = t; i < 66 * 21; i += 256) {
    int r = i / 21, f = i - r * 21;
    int l = (l0 - 1 + r) & (L - 1);
    xs[r][f] = x[((size_t)b * L + l) * NF + f];
  }
  for (int i = t; i < 63 * 64; i += 256) {
    int k = i >> 6, dd = i & 63;
    wt[k][dd] = W[(size_t)(d0 + dd) * 63 + k];
  }
  __syncthreads();
  int tx = t & 15, ty = t >> 4;
  float acc[4][4] = {};
  #pragma unroll
  for (int f = 0; f < 21; ++f) {
    #pragma unroll
    for (int j = 0; j < 3; ++j) {
      int k = f * 3 + j;
      float xv[4], wv[4];
      #pragma unroll
      for (int i = 0; i < 4; ++i) xv[i] = xs[ty * 4 + i + j][f];
      #pragma unroll
      for (int jj = 0; jj < 4; ++jj) wv[jj] = wt[k][tx * 4 + jj];
      #pragma unroll
      for (int i = 0; i < 4; ++i)
        #pragma unroll
        for (int jj = 0; jj < 4; ++jj) acc[i][jj] += xv[i] * wv[jj];
    }
  }
  #pragma unroll
  for (int i = 0; i < 4; ++i) {
    int l = l0 + ty * 4 + i;
    #pragma unroll
    for (int jj = 0; jj < 4; ++jj) {
      int d = d0 + tx * 4 + jj;
      float dv = expf((float)(d & ~1) * (-9.210340371976184f / 512.0f));
      float ang = (float)l * dv;
      float pe = (d & 1) ? cosf(ang) : sinf(ang);
      float v = acc[i][jj] + pe;
      size_t o = ((size_t)b * L + l) * Dm + d;
      out[o] = v;
      outb[o] = f2b(v);
    }
  }
}

// ---------------- pure-bf16 MFMA GEMM, global_load_lds staging ----------------
// 128x128 tile, BK=64, m97 2-barrier structure; swizzle folded into per-lane global src.
// MODE 0: fp32 out, bias+res; 1: bf16 out, bias; 2: bf16 out, gelu; 3: fp32 out, res
template<int MODE>
__global__ __launch_bounds__(256) void k_bgemm3(const short* __restrict__ A,
                       const short* __restrict__ W,
                       const float* __restrict__ bias, const float* __restrict__ R,
                       void* __restrict__ Cv, int N, int K) {
  __shared__ __align__(16) short As[128 * 64];
  __shared__ __align__(16) short Bs[128 * 64];
  int nt = N >> 7;
  int n0 = (blockIdx.x % nt) << 7;
  int m0 = (int)(blockIdx.x / nt) << 7;
  int t = threadIdx.x;
  int lane = t & 63, w = t >> 6;
  int wr = (w >> 1) << 6, wc = (w & 1) << 6;
  int fr_a = wr + (lane & 15);
  int fr_b = wc + (lane & 15);
  int cbase = lane >> 4;
  // staging geometry: linear LDS chunk ch = (w*4+i)*64 + lane; inverse-swizzled global src
  int rs[4], gko[4];
  #pragma unroll
  for (int i = 0; i < 4; ++i) {
    int ch = (w * 4 + i) * 64 + lane;
    rs[i] = ch >> 3;
    gko[i] = ((ch & 7) ^ (rs[i] & 7)) << 3;
  }
  f32x4 acc[4][4] = {};
  for (int k0 = 0; k0 < K; k0 += 64) {
    __syncthreads();
    #pragma unroll
    for (int i = 0; i < 4; ++i) {
      __builtin_amdgcn_global_load_lds(
          (const unsigned int*)(A + (size_t)(m0 + rs[i]) * K + k0 + gko[i]),
          (unsigned int*)(As + ((w * 4 + i) << 9)), 16, 0, 0);
      __builtin_amdgcn_global_load_lds(
          (const unsigned int*)(W + (size_t)(n0 + rs[i]) * K + k0 + gko[i]),
          (unsigned int*)(Bs + ((w * 4 + i) << 9)), 16, 0, 0);
    }
    __syncthreads();
    #pragma unroll
    for (int ks = 0; ks < 2; ++ks) {
      int c = cbase + ks * 4;
      s16x8 af[4], bf_[4];
      #pragma unroll
      for (int f = 0; f < 4; ++f) {
        int r1 = fr_a + f * 16;
        af[f] = *(const s16x8*)(As + r1 * 64 + ((c ^ (r1 & 7)) << 3));
        int r2 = fr_b + f * 16;
        bf_[f] = *(const s16x8*)(Bs + r2 * 64 + ((c ^ (r2 & 7)) << 3));
      }
      #pragma unroll
      for (int fm = 0; fm < 4; ++fm)
        #pragma unroll
        for (int fn = 0; fn < 4; ++fn)
          acc[fm][fn] = __builtin_amdgcn_mfma_f32_16x16x32_bf16(af[fm], bf_[fn], acc[fm][fn], 0, 0, 0);
    }
  }
  int em = m0 + wr + ((lane >> 4) << 2);
  int en = n0 + wc + (lane & 15);
  #pragma unroll
  for (int fm = 0; fm < 4; ++fm) {
    #pragma unroll
    for (int fn = 0; fn < 4; ++fn) {
      int n = en + fn * 16;
      #pragma unroll
      for (int r = 0; r < 4; ++r) {
        int m = em + fm * 16 + r;
        float vv = acc[fm][fn][r];
        if (MODE == 0 || MODE == 1) vv += bias[n];
        if (MODE == 2) vv = 0.5f * vv * (1.0f + erff(vv * 0.70710678118654752f));
        if (MODE == 0 || MODE == 3) {
          vv += R[(size_t)m * N + n];
          ((float*)Cv)[(size_t)m * N + n] = vv;
        } else {
          ((short*)Cv)[(size_t)m * N + n] = f2b(vv);
        }
      }
    }
  }
}

// ---------------- twiddle tables (bf16) ----------------
__global__ void k_gentw(short* __restrict__ fm, short* __restrict__ gt) {
  int idx = blockIdx.x * 256 + threadIdx.x;
  {
    int m2 = idx >> 12, l = idx & 4095;
    int m = m2 & 63;
    int ph = (m * l) & (L - 1);
    float sv, cv;
    __sincosf((float)ph * (TWOPI / L), &sv, &cv);
    fm[idx] = f2b((m2 < 64) ? cv : -sv);
  }
  {
    int l = idx >> 7, m2 = idx & 127;
    int m = m2 & 63;
    int ph = (m * l) & (L - 1);
    float sv, cv;
    __sincosf((float)ph * (TWOPI / L), &sv, &cv);
    float g;
    if (m2 == 0) g = 1.0f;
    else if (m2 == 64) g = 0.0f;
    else g = (m2 < 64) ? 2.0f * cv : -2.0f * sv;
    gt[idx] = f2b(g);
  }
}

// ---------------- MFMA forward DFT (bf16 input): S[b][c][m2] += sum_l A[b][l][c]*Fm[m2][l] ----------------
__global__ __launch_bounds__(256) void k_dft_mfma(const short* __restrict__ A,
                                                  const short* __restrict__ Fm,
                                                  float* __restrict__ S) {
  __shared__ __align__(16) short As[128 * 128];
  __shared__ __align__(16) short Bs[128 * 128];
  int bid = blockIdx.x;
  int kseg = bid & 15, ct = (bid >> 4) & 3, b = bid >> 6;
  int c0 = ct << 7;
  int lbase = kseg << 8;
  int t = threadIdx.x;
  int lane = t & 63, w = t >> 6;
  int wr = (w >> 1) << 6, wc = (w & 1) << 6;
  f32x4 acc[4][4] = {};
  const short* Ab = A + (size_t)b * L * Dm;

  for (int k0 = 0; k0 < 256; k0 += 128) {
    if (k0) __syncthreads();
    // stage A: transpose bf16 (l,c) -> LDS [c][l]
    #pragma unroll
    for (int it = 0; it < 4; ++it) {
      int s = it * 256 + t;
      int cq = (s & 31) << 2;
      int lq = (s >> 5) << 2;
      const short* base = Ab + (size_t)(lbase + k0 + lq) * Dm + c0 + cq;
      s16x4 r0 = *(const s16x4*)(base);
      s16x4 r1 = *(const s16x4*)(base + Dm);
      s16x4 r2 = *(const s16x4*)(base + 2 * Dm);
      s16x4 r3 = *(const s16x4*)(base + 3 * Dm);
      #pragma unroll
      for (int j = 0; j < 4; ++j) {
        int crow = cq + j;
        s16x4 p;
        p[0] = r0[j]; p[1] = r1[j]; p[2] = r2[j]; p[3] = r3[j];
        *(s16x4*)((char*)As + crow * 256 + ((lq * 2) ^ ((crow & 15) << 4))) = p;
      }
    }
    // stage B: Fm rows
    #pragma unroll
    for (int it = 0; it < 8; ++it) {
      int m = it * 16 + (t >> 4);
      int lb = (t & 15) * 8;
      s16x8 vv = *(const s16x8*)(Fm + (size_t)m * L + lbase + k0 + lb);
      *(s16x8*)((char*)Bs + m * 256 + ((lb * 2) ^ ((m & 15) << 4))) = vv;
    }
    __syncthreads();
    #pragma unroll
    for (int ks = 0; ks < 4; ++ks) {
      int kb = ks * 64 + ((lane >> 4) << 4);
      s16x8 af[4], bf_[4];
      #pragma unroll
      for (int f = 0; f < 4; ++f) {
        int fr = wr + (lane & 15) + f * 16;
        af[f] = *(const s16x8*)((const char*)As + fr * 256 + (kb ^ ((fr & 15) << 4)));
        int mr = wc + (lane & 15) + f * 16;
        bf_[f] = *(const s16x8*)((const char*)Bs + mr * 256 + (kb ^ ((mr & 15) << 4)));
      }
      #pragma unroll
      for (int fm = 0; fm < 4; ++fm)
        #pragma unroll
        for (int fn = 0; fn < 4; ++fn)
          acc[fm][fn] = __builtin_amdgcn_mfma_f32_16x16x32_bf16(af[fm], bf_[fn], acc[fm][fn], 0, 0, 0);
    }
  }
  float* Sb = S + (size_t)b * Dm * 128;
  int ec = c0 + wr + ((lane >> 4) << 2);
  int em = wc + (lane & 15);
  #pragma unroll
  for (int fm = 0; fm < 4; ++fm)
    #pragma unroll
    for (int fn = 0; fn < 4; ++fn)
      #pragma unroll
      for (int r = 0; r < 4; ++r)
        atomicAdd(&Sb[(size_t)(ec + fm * 16 + r) * 128 + em + fn * 16], acc[fm][fn][r]);
}

// ---------------- MFMA inverse DFT: O[b][c][l] = scale * sum_m S[b][c][m]*Gt[l][m], bf16 out ----------------
__global__ __launch_bounds__(256) void k_irdft_mfma(const float* __restrict__ S,
                                                    const short* __restrict__ Gt,
                                                    short* __restrict__ O, float scale) {
  __shared__ __align__(16) short As[128 * 128];
  __shared__ __align__(16) short Bs[128 * 128];
  int bid = blockIdx.x;
  int lt = bid & 31, ct = (bid >> 5) & 3, b = bid >> 7;
  int c0 = ct << 7;
  int l0t = lt << 7;
  int t = threadIdx.x;
  int lane = t & 63, w = t >> 6;
  int wr = (w >> 1) << 6, wc = (w & 1) << 6;
  f32x4 acc[4][4] = {};
  #pragma unroll
  for (int it = 0; it < 8; ++it) {
    int c = it * 16 + (t >> 4);
    int me = (t & 15) * 8;
    const float* sp = S + ((size_t)b * Dm + c0 + c) * 128 + me;
    f32x4 v0 = *(const f32x4*)sp;
    f32x4 v1 = *(const f32x4*)(sp + 4);
    s16x8 p;
    p[0]=f2b(v0[0]); p[1]=f2b(v0[1]); p[2]=f2b(v0[2]); p[3]=f2b(v0[3]);
    p[4]=f2b(v1[0]); p[5]=f2b(v1[1]); p[6]=f2b(v1[2]); p[7]=f2b(v1[3]);
    *(s16x8*)((char*)As + c * 256 + ((me * 2) ^ ((c & 15) << 4))) = p;
  }
  #pragma unroll
  for (int it = 0; it < 8; ++it) {
    int l = it * 16 + (t >> 4);
    int me = (t & 15) * 8;
    s16x8 vv = *(const s16x8*)(Gt + (size_t)(l0t + l) * 128 + me);
    *(s16x8*)((char*)Bs + l * 256 + ((me * 2) ^ ((l & 15) << 4))) = vv;
  }
  __syncthreads();
  #pragma unroll
  for (int ks = 0; ks < 4; ++ks) {
    int kb = ks * 64 + ((lane >> 4) << 4);
    s16x8 af[4], bf_[4];
    #pragma unroll
    for (int f = 0; f < 4; ++f) {
      int fr = wr + (lane & 15) + f * 16;
      af[f] = *(const s16x8*)((const char*)As + fr * 256 + (kb ^ ((fr & 15) << 4)));
      int lr = wc + (lane & 15) + f * 16;
      bf_[f] = *(const s16x8*)((const char*)Bs + lr * 256 + (kb ^ ((lr & 15) << 4)));
    }
    #pragma unroll
    for (int fm = 0; fm < 4; ++fm)
      #pragma unroll
      for (int fn = 0; fn < 4; ++fn)
        acc[fm][fn] = __builtin_amdgcn_mfma_f32_16x16x32_bf16(af[fm], bf_[fn], acc[fm][fn], 0, 0, 0);
  }
  short* Ob = O + (size_t)b * Dm * L;
  int ec = c0 + wr + ((lane >> 4) << 2);
  int el = l0t + wc + (lane & 15);
  #pragma unroll
  for (int fm = 0; fm < 4; ++fm)
    #pragma unroll
    for (int fn = 0; fn < 2 * 2; ++fn)
      ;
  #pragma unroll
  for (int fm = 0; fm < 4; ++fm)
    #pragma unroll
    for (int fn = 0; fn < 4; ++fn)
      #pragma unroll
      for (int r = 0; r < 4; ++r)
        Ob[(size_t)(ec + fm * 16 + r) * L + el + fn * 16] = f2b(scale * acc[fm][fn][r]);
}

// ---------------- per-mode complex channel mix ----------------
__global__ __launch_bounds__(256) void k_cmul2(const float* __restrict__ S, const float* __restrict__ Wf,
                                               float* __restrict__ O) {
  __shared__ float q[64 * 128];
  int bid = blockIdx.x;
  int og = bid & 3, h = (bid >> 2) & 7, b = bid >> 5;
  int t = threadIdx.x;
  const float* Sb = S + ((size_t)b * Dm + h * NE) * 128;
  for (int i = t; i < 8192; i += 256) q[i] = Sb[i];
  __syncthreads();
  int o = og * 16 + (t >> 4);
  int m0 = (t & 15) * 4;
  float ar[4] = {}, ai[4] = {};
  for (int i = 0; i < 64; ++i) {
    const float* wrow = Wf + (((size_t)h * 64 + i) * 64 + o) * 128 + m0 * 2;
    float wv[8];
    *(f32x4*)wv = *(const f32x4*)wrow;
    *(f32x4*)(wv + 4) = *(const f32x4*)(wrow + 4);
    const float* qi_ = q + i * 128;
    #pragma unroll
    for (int k = 0; k < 4; ++k) {
      float qr = qi_[m0 + k], qim = qi_[64 + m0 + k];
      float wr = wv[2 * k], wi = wv[2 * k + 1];
      ar[k] += qr * wr - qim * wi;
      ai[k] += qr * wi + qim * wr;
    }
  }
  float* Ob = O + ((size_t)b * Dm + h * NE + o) * 128;
  f32x4 vr, vi;
  #pragma unroll
  for (int k = 0; k < 4; ++k) { vr[k] = ar[k]; vi[k] = ai[k]; }
  *(f32x4*)(Ob + m0) = vr;
  *(f32x4*)(Ob + 64 + m0) = vi;
}

// ---------------- cross: s[x,y] = ctanh(sum_e qf[e,x]*kf[e,y]) ----------------
__global__ void k_cross_s(const float* __restrict__ Sq, const float* __restrict__ Sk,
                          float* __restrict__ Sout) {
  int bh = blockIdx.x;
  int b = bh >> 3, h = bh & 7;
  __shared__ float Qr[64][64], Qi[64][64], Kr[64][64], Ki[64][64];
  int t = threadIdx.x;
  const float* qb = Sq + ((size_t)b * Dm + h * NE) * 128;
  const float* kb = Sk + ((size_t)b * Dm + h * NE) * 128;
  for (int idx = t; idx < 4096; idx += 256) {
    int e = idx >> 6, x = idx & 63;
    Qr[e][x] = qb[e * 128 + x];
    Qi[e][x] = qb[e * 128 + 64 + x];
    Kr[e][x] = kb[e * 128 + x];
    Ki[e][x] = kb[e * 128 + 64 + x];
  }
  __syncthreads();
  int tx = t & 15, ty = t >> 4;
  float ar[4][4] = {}, ai[4][4] = {};
  for (int e = 0; e < 64; ++e) {
    float qr[4], qi[4], kr[4], ki[4];
    #pragma unroll
    for (int i = 0; i < 4; ++i) { qr[i] = Qr[e][(ty << 2) + i]; qi[i] = Qi[e][(ty << 2) + i]; }
    #pragma unroll
    for (int j = 0; j < 4; ++j) { kr[j] = Kr[e][(tx << 2) + j]; ki[j] = Ki[e][(tx << 2) + j]; }
    #pragma unroll
    for (int i = 0; i < 4; ++i)
      #pragma unroll
      for (int j = 0; j < 4; ++j) {
        ar[i][j] += qr[i] * kr[j] - qi[i] * ki[j];
        ai[i][j] += qr[i] * ki[j] + qi[i] * kr[j];
      }
  }
  float* sp = Sout + (size_t)bh * 4096 * 2;
  #pragma unroll
  for (int i = 0; i < 4; ++i)
    #pragma unroll
    for (int j = 0; j < 4; ++j) {
      int x = (ty << 2) + i, y = (tx << 2) + j;
      float a = ar[i][j], bb = ai[i][j];
      float th = tanhf(a);
      float u = tanf(bb);
      float re, im;
      if (fabsf(u) <= 1.0f) {
        float dn = 1.0f + th * th * u * u;
        re = th * (1.0f + u * u) / dn;
        im = u * (1.0f - th * th) / dn;
      } else {
        float iu = 1.0f / u;
        float dn = iu * iu + th * th;
        re = th * (iu * iu + 1.0f) / dn;
        im = iu * (1.0f - th * th) / dn;
      }
      sp[(x * 64 + y) * 2]     = re;
      sp[(x * 64 + y) * 2 + 1] = im;
    }
}

// ---------------- cross: o[e,x] = sum_y s[x,y]*kf[e,y] ----------------
__global__ void k_cross_o(const float* __restrict__ Sin, const float* __restrict__ Sk,
                          float* __restrict__ O2) {
  int bh = blockIdx.x;
  int b = bh >> 3, h = bh & 7;
  __shared__ float SrT[64][64], SiT[64][64], KrT[64][64], KiT[64][64];
  int t = threadIdx.x;
  const float* sp = Sin + (size_t)bh * 8192;
  const float* kb = Sk + ((size_t)b * Dm + h * NE) * 128;
  for (int idx = t; idx < 4096; idx += 256) {
    int r = idx >> 6, c = idx & 63;
    SrT[c][r] = sp[idx * 2];
    SiT[c][r] = sp[idx * 2 + 1];
    KrT[c][r] = kb[r * 128 + c];
    KiT[c][r] = kb[r * 128 + 64 + c];
  }
  __syncthreads();
  int tx = t & 15, ty = t >> 4;
  float ar[4][4] = {}, ai[4][4] = {};
  for (int y = 0; y < 64; ++y) {
    float kr[4], ki[4], sr[4], si[4];
    #pragma unroll
    for (int i = 0; i < 4; ++i) { kr[i] = KrT[y][(ty << 2) + i]; ki[i] = KiT[y][(ty << 2) + i]; }
    #pragma unroll
    for (int j = 0; j < 4; ++j) { sr[j] = SrT[y][(tx << 2) + j]; si[j] = SiT[y][(tx << 2) + j]; }
    #pragma unroll
    for (int i = 0; i < 4; ++i)
      #pragma unroll
      for (int j = 0; j < 4; ++j) {
        ar[i][j] += sr[j] * kr[i] - si[j] * ki[i];
        ai[i][j] += sr[j] * ki[i] + si[j] * kr[i];
      }
  }
  float* ob = O2 + ((size_t)b * Dm + h * NE) * 128;
  #pragma unroll
  for (int i = 0; i < 4; ++i)
    #pragma unroll
    for (int j = 0; j < 4; ++j) {
      int e = (ty << 2) + i, x = (tx << 2) + j;
      ob[e * 128 + x]      = ar[i][j];
      ob[e * 128 + 64 + x] = ai[i][j];
    }
}

// ---------------- series_decomp sliding window, dual out ----------------
template<int TMODE> // 0 none, 1 write trend, 2 add trend, 3 add trend -> bf16 Tb
__global__ __launch_bounds__(512) void k_decomp3(const float* __restrict__ Z, float* __restrict__ Sout,
                          short* __restrict__ Sb, float* __restrict__ T, short* __restrict__ Tb) {
  int b = blockIdx.x >> 7;
  int l0 = (blockIdx.x & 127) << 5;
  int d = threadIdx.x;
  const float* zb = Z + (size_t)b * L * Dm + d;
  float s = 0.f;
  #pragma unroll
  for (int j = -12; j <= 12; ++j) {
    int ll = l0 + j; ll = ll < 0 ? 0 : ll;
    s += zb[(size_t)ll * Dm];
  }
  for (int i = 0; i < 32; ++i) {
    int l = l0 + i;
    float ma = s * (1.0f / 25.0f);
    size_t idx = ((size_t)b * L + l) * Dm + d;
    float se = zb[(size_t)l * Dm] - ma;
    Sout[idx] = se;
    Sb[idx] = f2b(se);
    if (TMODE == 1) T[idx] = ma;
    else if (TMODE == 2) T[idx] += ma;
    else if (TMODE == 3) Tb[idx] = f2b(T[idx] + ma);
    int la = l + 13; la = la > L - 1 ? L - 1 : la;
    int lr = l - 12; lr = lr < 0 ? 0 : lr;
    s += zb[(size_t)la * Dm] - zb[(size_t)lr * Dm];
  }
}

// ---------------- row LayerNorm over Dm ----------------
__global__ void k_ln(const float* __restrict__ X, const float* __restrict__ g,
                     const float* __restrict__ be, float* __restrict__ Y) {
  int row = blockIdx.x;
  const float* x = X + (size_t)row * Dm;
  int t = threadIdx.x;
  float v0 = x[t], v1 = x[t + 256];
  float s = v0 + v1;
  __shared__ float red[4];
  #pragma unroll
  for (int off = 32; off > 0; off >>= 1) s += __shfl_down(s, off);
  int wid = t >> 6, lane = t & 63;
  if (lane == 0) red[wid] = s;
  __syncthreads();
  float mu = (red[0] + red[1] + red[2] + red[3]) * (1.0f / Dm);
  float e0 = v0 - mu, e1 = v1 - mu;
  float s2 = e0 * e0 + e1 * e1;
  #pragma unroll
  for (int off = 32; off > 0; off >>= 1) s2 += __shfl_down(s2, off);
  __syncthreads();
  if (lane == 0) red[wid] = s2;
  __syncthreads();
  float var = (red[0] + red[1] + red[2] + red[3]) * (1.0f / Dm);
  float rstd = rsqrtf(var + 1e-5f);
  float* y = Y + (size_t)row * Dm;
  y[t]       = e0 * rstd * g[t] + be[t];
  y[t + 256] = e1 * rstd * g[t + 256] + be[t + 256];
}

// ---------------- column sums over time ----------------
__global__ void k_colsum(const float* __restrict__ X, float* __restrict__ cm) {
  int b = blockIdx.x;
  int d = blockIdx.y * 256 + threadIdx.x;
  int lc = blockIdx.z;
  const float* x = X + ((size_t)b * L + (size_t)lc * 128) * Dm + d;
  float s = 0.f;
  for (int i = 0; i < 128; ++i) s += x[(size_t)i * Dm];
  atomicAdd(&cm[b * Dm + d], s);
}

// my_layernorm finish: bf16 out only
__global__ void k_sub2(const float* __restrict__ X, const float* __restrict__ cm,
                       short* __restrict__ Y) {
  size_t idx = (size_t)blockIdx.x * 256 + threadIdx.x;
  int d = (int)(idx & (Dm - 1));
  int b = (int)(idx >> 21);
  Y[idx] = f2b(X[idx] - cm[b * Dm + d] * (1.0f / L));
}

// ---------------- trend projection as MFMA GEMM ----------------
// RT[m][f] = sum_j sum_d Tb[b, (l+j-1)&4095, d] * Wt3[j][f][d];  M tile 64, N=32 (21 used)
__global__ __launch_bounds__(256) void k_trendproj4(const short* __restrict__ Tb,
                                                    const short* __restrict__ Wt3,
                                                    float* __restrict__ RT) {
  __shared__ __align__(16) short As[64 * 64];
  __shared__ __align__(16) short Bs[32 * 64];
  int m0 = blockIdx.x << 6;
  int t = threadIdx.x, lane = t & 63, w = t >> 6;
  int fr_a = (w << 4) + (lane & 15);
  int cbase = lane >> 4;
  f32x4 acc[2] = {};
  int srow = t >> 2;            // 0..63
  int ca = (t & 3) * 2;         // two A chunks per thread
  int nB = t >> 3;              // 0..31
  int ckB = t & 7;              // one B chunk per thread
  int mrow = m0 + srow;
  int bb = mrow >> 12, ll = mrow & 4095;
  for (int j = 0; j < 3; ++j) {
    int lsrc = (ll + j - 1) & 4095;
    const short* Arow = Tb + (((size_t)(bb << 12) + lsrc) << 9);
    const short* Brow = Wt3 + (j << 14) + (nB << 9);
    for (int k0 = 0; k0 < 512; k0 += 64) {
      __syncthreads();
      #pragma unroll
      for (int q = 0; q < 2; ++q) {
        int c = ca + q;
        s16x8 v = *(const s16x8*)(Arow + k0 + (c << 3));
        *(s16x8*)(As + srow * 64 + ((c ^ (srow & 7)) << 3)) = v;
      }
      {
        s16x8 v = *(const s16x8*)(Brow + k0 + (ckB << 3));
        *(s16x8*)(Bs + nB * 64 + ((ckB ^ (nB & 7)) << 3)) = v;
      }
      __syncthreads();
      #pragma unroll
      for (int ks = 0; ks < 2; ++ks) {
        int c = cbase + ks * 4;
        s16x8 af = *(const s16x8*)(As + fr_a * 64 + ((c ^ (fr_a & 7)) << 3));
        #pragma unroll
        for (int fn = 0; fn < 2; ++fn) {
          int r2 = (lane & 15) + fn * 16;
          s16x8 bf_ = *(const s16x8*)(Bs + r2 * 64 + ((c ^ (r2 & 7)) << 3));
          acc[fn] = __builtin_amdgcn_mfma_f32_16x16x32_bf16(af, bf_, acc[fn], 0, 0, 0);
        }
      }
    }
  }
  int em = m0 + (w << 4) + ((lane >> 4) << 2);
  int en = lane & 15;
  #pragma unroll
  for (int fn = 0; fn < 2; ++fn) {
    int n = en + fn * 16;
    if (n < NF) {
      #pragma unroll
      for (int r = 0; r < 4; ++r)
        RT[(size_t)(em + r) * NF + n] = acc[fn][r];
    }
  }
}

// ---------------- final: out = tinit + RT + my_ln(x) @ Wf^T + bf ----------------
__global__ void k_final(const float* __restrict__ X, const float* __restrict__ cm,
                        const float* __restrict__ Wf, const float* __restrict__ bf,
                        const float* __restrict__ tinit, const float* __restrict__ RT,
                        float* __restrict__ out) {
  int bt = blockIdx.x; int b = bt / PRED, tt = bt % PRED;
  int l = LABEL + tt;
  __shared__ float row[512];
  __shared__ float partial[NF][9];
  int t = threadIdx.x;
  const float* x = X + ((size_t)b * L + l) * Dm;
  const float* c = cm + b * Dm;
  row[t]       = x[t]       - c[t]       * (1.0f / L);
  row[t + 256] = x[t + 256] - c[t + 256] * (1.0f / L);
  __syncthreads();
  if (t < 168) {
    int f = t >> 3, p = t & 7;
    const float* w = Wf + (size_t)f * Dm + p * 64;
    float s = 0.f;
    #pragma unroll
    for (int q = 0; q < 64; ++q) s += row[p * 64 + q] * w[q];
    partial[f][p] = s;
  }
  __syncthreads();
  if (t < NF) {
    float s = bf[t];
    #pragma unroll
    for (int p = 0; p < 8; ++p) s += partial[t][p];
    size_t src = ((size_t)b * L + l) * NF + t;
    out[((size_t)b * PRED + tt) * NF + t] = s + tinit[src] + RT[src];
  }
}

} // namespace

extern "C" void kernel_launch(void* const* d_in, const int* in_sizes, int n_in,
                              void* d_out, int out_size, void* d_ws, size_t ws_size,
                              hipStream_t stream) {
  (void)in_sizes; (void)n_in; (void)out_size; (void)ws_size;
  const float* x_enc              = (const float*)d_in[0];
  const float* enc_emb_W          = (const float*)d_in[3];
  const float* dec_emb_W          = (const float*)d_in[4];
  const float* enc_qkvo_W         = (const float*)d_in[5];
  const float* enc_qkvo_b         = (const float*)d_in[6];
  const float* enc_ffn_W1         = (const float*)d_in[7];
  const float* enc_ffn_W2         = (const float*)d_in[8];
  const float* enc_fourier_W      = (const float*)d_in[9];
  const float* enc_norm_g         = (const float*)d_in[10];
  const float* enc_norm_b         = (const float*)d_in[11];
  const float* dec_qkvo_W         = (const float*)d_in[12];
  const float* dec_qkvo_b         = (const float*)d_in[13];
  const float* dec_ffn_W1         = (const float*)d_in[14];
  const float* dec_ffn_W2         = (const float*)d_in[15];
  const float* dec_self_fourier_W = (const float*)d_in[16];
  const float* dec_cross_fourier_W= (const float*)d_in[17];
  const float* dec_trend_proj_W   = (const float*)d_in[18];
  const float* dec_norm_g         = (const float*)d_in[19];
  const float* dec_norm_b         = (const float*)d_in[20];
  const float* final_W            = (const float*)d_in[21];
  const float* final_b            = (const float*)d_in[22];
  float* out = (float*)d_out;

  // ---- workspace: 58,468,480 floats = 223 MiB (< 236 MiB proven-safe) ----
  float* ws = (float*)d_ws;
  const size_t SZ = (size_t)NB * L * Dm;     // 8,388,608
  float* S_x   = ws;
  float* S_dec = ws + SZ;
  float* S_z   = ws + 2 * SZ;
  float* T_sum = ws + 3 * SZ;
  short* act   = (short*)(ws + 4 * SZ);      // 2*SZ shorts: H1 | H2
  short* S_qb  = act;
  short* S_xb  = act + SZ;
  short* H16   = act;                        // FFN hidden 8192x2048
  short* S_eb  = (short*)(ws + 5 * SZ);      // SZ shorts
  short* W16   = (short*)(ws + 5 * SZ + SZ / 2);  // 10,485,760 shorts
  float* sm = ws + 5 * SZ + SZ / 2 + 5242880;
  float* spec_q  = sm; sm += 262144;
  float* spec_k  = sm; sm += 262144;
  float* spec_o  = sm; sm += 262144;
  float* spec_o2 = sm; sm += 262144;
  float* spec_s  = sm; sm += 262144;
  float* mean_bf = sm; sm += 128;
  float* cm      = sm; sm += 2048;
  float* sinit   = sm; sm += (size_t)NB * L * NF;
  float* tinit   = sm; sm += (size_t)NB * L * NF;
  float* RT      = sm; sm += (size_t)NB * L * NF;
  short* fm_tw   = (short*)sm; sm += 262144;
  short* gt_tw   = (short*)sm; sm += 262144;
  short* tb16    = (short*)sm; sm += SZ / 2;      // SZ shorts (bf16 trend)
  short* wt3     = (short*)sm; sm += 49152;       // 3*32*512 shorts (over-alloc ok)

  short* w16_eq = W16;
  short* w16_e1 = W16 + 2097152;
  short* w16_e2 = W16 + 4194304;
  short* w16_dq = W16 + 6291456;
  short* w16_d1 = W16 + 8388608;
  short* w16_d2 = W16 + 9437184;

  auto cvt = [&](const float* s, short* d, int n) {
    k_cvt<<<(n / 4 + 255) / 256, 256, 0, stream>>>(s, d, n);
  };
  auto gemm = [&](int mode, const short* A, const short* Wt, const float* bias,
                  const float* R, void* C, int Mr, int N, int K) {
    dim3 grid((unsigned)((Mr >> 7) * (N >> 7)));
    if (mode == 0)      k_bgemm3<0><<<grid, 256, 0, stream>>>(A, Wt, bias, R, C, N, K);
    else if (mode == 1) k_bgemm3<1><<<grid, 256, 0, stream>>>(A, Wt, bias, R, C, N, K);
    else if (mode == 2) k_bgemm3<2><<<grid, 256, 0, stream>>>(A, Wt, bias, R, C, N, K);
    else                k_bgemm3<3><<<grid, 256, 0, stream>>>(A, Wt, bias, R, C, N, K);
  };
  auto dft = [&](const short* A, float* S) {
    hipMemsetAsync(S, 0, 262144 * sizeof(float), stream);
    k_dft_mfma<<<256, 256, 0, stream>>>(A, fm_tw, S);
  };
  auto irdft = [&](const float* S, short* O, float scale) {
    k_irdft_mfma<<<512, 256, 0, stream>>>(S, gt_tw, O, scale);
  };
  auto decomp = [&](int tmode, const float* Z, float* Sout, short* Sb, float* T, short* Tb) {
    if (tmode == 0)      k_decomp3<0><<<NB * 128, 512, 0, stream>>>(Z, Sout, Sb, T, Tb);
    else if (tmode == 1) k_decomp3<1><<<NB * 128, 512, 0, stream>>>(Z, Sout, Sb, T, Tb);
    else if (tmode == 2) k_decomp3<2><<<NB * 128, 512, 0, stream>>>(Z, Sout, Sb, T, Tb);
    else                 k_decomp3<3><<<NB * 128, 512, 0, stream>>>(Z, Sout, Sb, T, Tb);
  };

  const int MR = NB * L;              // 16384
  const int RW = 8192;
  const size_t CH = (size_t)RW * Dm;
  const int QQ = 262144;              // 512*512

  // ---- Phase A: weights->bf16, twiddles, init, embed ----
  k_gentw<<<2048, 256, 0, stream>>>(fm_tw, gt_tw);
  cvt(enc_qkvo_W, w16_eq, 2097152);
  cvt(enc_ffn_W1, w16_e1, 2097152);
  cvt(enc_ffn_W2, w16_e2, 2097152);
  cvt(dec_qkvo_W, w16_dq, 2097152);
  cvt(dec_ffn_W1, w16_d1, 1048576);
  cvt(dec_ffn_W2, w16_d2, 1048576);
  k_prepw<<<192, 256, 0, stream>>>(dec_trend_proj_W, wt3);
  k_enc_mean<<<NB * NF, 256, 0, stream>>>(x_enc, mean_bf);
  k_init_decomp<<<(NB * L * NF + 255) / 256, 256, 0, stream>>>(x_enc, mean_bf, sinit, tinit);
  k_embed2<<<NB * 512, 256, 0, stream>>>(x_enc, enc_emb_W, S_x, S_eb);

  // ---- Phase B: encoder x2 ----
  for (int layer = 0; layer < 2; ++layer) {
    const short* Wl = w16_eq + (size_t)layer * 4 * QQ;
    const float* bl = enc_qkvo_b + (size_t)layer * 4 * Dm;
    gemm(1, S_eb, Wl, bl, nullptr, S_qb, MR, Dm, Dm);
    dft(S_qb, spec_q);
    k_cmul2<<<128, 256, 0, stream>>>(spec_q, enc_fourier_W, spec_o);
    irdft(spec_o, S_xb, 1.0f / L);
    gemm(0, S_xb, Wl + 3 * QQ, bl + 3 * Dm, S_x, S_z, MR, Dm, Dm);
    decomp(0, S_z, S_x, S_eb, nullptr, nullptr);
    for (int ch = 0; ch < 2; ++ch) {
      gemm(2, S_eb + (size_t)ch * CH, w16_e1 + (size_t)layer * DFF * Dm, nullptr, nullptr,
           H16, RW, DFF, Dm);
      gemm(3, H16, w16_e2 + (size_t)layer * Dm * DFF, nullptr, S_x + ch * CH,
           S_z + ch * CH, RW, Dm, DFF);
    }
    decomp(0, S_z, S_x, S_eb, nullptr, nullptr);
  }
  // my_layernorm(enc_out) -> bf16 in S_eb
  k_ln<<<NB * L, 256, 0, stream>>>(S_x, enc_norm_g, enc_norm_b, S_z);
  hipMemsetAsync(cm, 0, 2048 * sizeof(float), stream);
  k_colsum<<<dim3(NB, 2, 32), 256, 0, stream>>>(S_z, cm);
  k_sub2<<<32768, 256, 0, stream>>>(S_z, cm, S_eb);

  // ---- Phase C: decoder ----
  k_embed2<<<NB * 512, 256, 0, stream>>>(sinit, dec_emb_W, S_dec, S_xb);
  // self attention
  {
    const short* Wl = w16_dq;
    const float* bl = dec_qkvo_b;
    gemm(1, S_xb, Wl, bl, nullptr, S_qb, MR, Dm, Dm);
    dft(S_qb, spec_q);
    k_cmul2<<<128, 256, 0, stream>>>(spec_q, dec_self_fourier_W, spec_o);
    irdft(spec_o, S_xb, 1.0f / L);
    gemm(0, S_xb, Wl + 3 * QQ, bl + 3 * Dm, S_dec, S_z, MR, Dm, Dm);
    decomp(1, S_z, S_x, S_xb, T_sum, nullptr);
  }
  // cross attention
  {
    const short* Wl = w16_dq + 4 * QQ;
    const float* bl = dec_qkvo_b + 4 * Dm;
    gemm(1, S_xb, Wl, bl, nullptr, S_qb, MR, Dm, Dm);
    gemm(1, S_eb, Wl + QQ, bl + Dm, nullptr, S_xb, MR, Dm, Dm);
    dft(S_qb, spec_q);
    dft(S_xb, spec_k);
    k_cross_s<<<NB * NH, 256, 0, stream>>>(spec_q, spec_k, spec_s);
    k_cross_o<<<NB * NH, 256, 0, stream>>>(spec_s, spec_k, spec_o2);
    k_cmul2<<<128, 256, 0, stream>>>(spec_o2, dec_cross_fourier_W, spec_o);
    irdft(spec_o, S_qb, (1.0f / L) / (512.0f * 512.0f));
    gemm(0, S_qb, Wl + 3 * QQ, bl + 3 * Dm, S_x, S_z, MR, Dm, Dm);
    decomp(2, S_z, S_dec, S_eb, T_sum, nullptr);
  }
  // ffn
  for (int ch = 0; ch < 2; ++ch) {
    gemm(2, S_eb + (size_t)ch * CH, w16_d1, nullptr, nullptr, H16, RW, DFF, Dm);
    gemm(3, H16, w16_d2, nullptr, S_dec + ch * CH, S_z + ch * CH, RW, Dm, DFF);
  }
  decomp(3, S_z, S_x, S_eb, T_sum, tb16);
  // trend projection (MFMA GEMM) + final
  k_trendproj4<<<256, 256, 0, stream>>>(tb16, wt3, RT);
  k_ln<<<NB * L, 256, 0, stream>>>(S_x, dec_norm_g, dec_norm_b, S_z);
  hipMemsetAsync(cm, 0, 2048 * sizeof(float), stream);
  k_colsum<<<dim3(NB, 2, 32), 256, 0, stream>>>(S_z, cm);
  k_final<<<NB * PRED, 256, 0, stream>>>(S_z, cm, final_W, final_b, tinit, RT, out);
}